// Round 3
// baseline (20548.068 us; speedup 1.0000x reference)
//
#include <hip/hip_runtime.h>
#include <hip/hip_fp16.h>
#include <hip/hip_bf16.h>
#include <math.h>

// ---------------- constants ----------------
constexpr int   N_   = 2048;
constexpr int   DF_  = 256;
constexpr int   J_   = 8;
constexpr int   ELLW_= 64;
constexpr int   M_   = 256;          // Chebyshev terms (degree 255)
constexpr float H_   = 1.01f;        // domain half-width  ([-0.01, 2.01])
constexpr float C0_  = 1.0f;         // domain center
constexpr float AF_  = 0.34657359027997264f;   // A = 3*ln(2)/6
constexpr float PI_F = 3.14159265358979323846f;

typedef float f4v __attribute__((ext_vector_type(4)));
typedef __attribute__((ext_vector_type(8))) short bf16x8;
typedef __attribute__((ext_vector_type(4))) float f32x4;
using u16 = unsigned short;

__device__ __forceinline__ u16 f2bf(float v) {
    __hip_bfloat16 h = __float2bfloat16(v);
    union { __hip_bfloat16 b; u16 u; } cv; cv.b = h; return cv.u;
}

// ---------------- filter functions ----------------
__device__ __forceinline__ float g_hat_f(float x) {
    float val = 0.5f + 0.5f * cosf(2.f * PI_F * (x / AF_ + 0.5f));
    return (x <= 0.f && x > -AF_) ? val : 0.f;
}
__device__ __forceinline__ float wavelet_f(float lamb, int j) {
    float lmin = expf(AF_ * ((j - 1) / 3.0f - 1.0f));
    float lam  = fmaxf(lamb, lmin);
    return g_hat_f(logf(lam) - AF_ * (j - 1) / 3.0f);
}
__device__ __forceinline__ float filter_eval(float lamb, int jf) {
    if (jf == 0) {
        float g3 = 0.f;
        for (int j = 2; j <= 8; ++j) { float w = wavelet_f(lamb, j); g3 += w * w; }
        return sqrtf(fmaxf(1.5f - g3, 0.f));
    }
    return wavelet_f(lamb, jf + 1);
}

// ---------------- setup kernels ----------------
__global__ __launch_bounds__(256) void deg_kernel(const float* __restrict__ W,
                                                  float* __restrict__ dh,
                                                  float* __restrict__ dr) {
    int i = blockIdx.x, t = threadIdx.x;
    const float4* row = (const float4*)(W + (size_t)i * N_);
    float s = 0.f;
    for (int c = t; c < N_ / 4; c += 256) { float4 v = row[c]; s += v.x + v.y + v.z + v.w; }
    __shared__ float red[256];
    red[t] = s; __syncthreads();
    for (int o = 128; o; o >>= 1) { if (t < o) red[t] += red[t + o]; __syncthreads(); }
    if (t == 0) {
        float deg = red[0];
        float dhi = 1.f / sqrtf(fmaxf(deg, 1.f));
        dh[i] = dhi;
        dr[i] = (dhi * dhi * deg - C0_) / H_;
    }
}

__global__ __launch_bounds__(64) void ell_kernel(const float* __restrict__ W,
                                                 const float* __restrict__ dh,
                                                 int* __restrict__ cnt,
                                                 int* __restrict__ cols,
                                                 float* __restrict__ vals) {
    int i = blockIdx.x, lane = threadIdx.x;
    const float* row = W + (size_t)i * N_;
    unsigned long long lt = (1ull << lane) - 1ull;
    int base = 0;
    float dhi = dh[i];
    for (int c = 0; c < N_; c += 64) {
        float v = row[c + lane];
        unsigned long long m = __ballot(v != 0.f);
        if (v != 0.f) {
            int pos = base + __popcll(m & lt);
            if (pos < ELLW_) {
                cols[i * ELLW_ + pos] = c + lane;
                vals[i * ELLW_ + pos] = dhi * dh[c + lane] / H_;
            }
        }
        base += __popcll(m);
    }
    if (lane == 0) cnt[i] = base < ELLW_ ? base : ELLW_;
}

__global__ __launch_bounds__(256) void coef_kernel(float* __restrict__ coefs) {
    __shared__ float fv[J_][M_];
    int t = threadIdx.x;
    float theta = PI_F * (t + 0.5f) / M_;
    float lam = C0_ + H_ * cosf(theta);
    for (int j = 0; j < J_; ++j) fv[j][t] = filter_eval(lam, j);
    __syncthreads();
    for (int j = 0; j < J_; ++j) {
        float s = 0.f;
        for (int i = 0; i < M_; ++i)
            s += fv[j][i] * cosf(PI_F * t * (i + 0.5f) / M_);
        coefs[j * M_ + t] = s * ((t == 0 ? 1.f : 2.f) / M_);
    }
}

__global__ __launch_bounds__(256) void init_T(float* __restrict__ T0, float* __restrict__ T1,
                                              __half* __restrict__ S0, __half* __restrict__ S1,
                                              const int* __restrict__ cnt, const int* __restrict__ cols,
                                              const float* __restrict__ vals, const float* __restrict__ dr) {
    int i = blockIdx.x, t = threadIdx.x;
    size_t ro = (size_t)i * N_;
    for (int c = t * 4; c < N_; c += 1024) {
        *(float4*)(T0 + ro + c) = float4{0, 0, 0, 0};
        *(float4*)(T1 + ro + c) = float4{0, 0, 0, 0};
        if (S0) { *(ushort4*)(S0 + ro + c) = ushort4{0, 0, 0, 0};
                  *(ushort4*)(S1 + ro + c) = ushort4{0, 0, 0, 0}; }
    }
    __syncthreads();
    int n = cnt[i];
    if (t < n) {
        int c = cols[i * ELLW_ + t];
        float v = -vals[i * ELLW_ + t];
        T1[ro + c] = v;
        if (S1) S1[ro + c] = __float2half(v);
    }
    if (t == 0) {
        T0[ro + i] = 1.f;
        T1[ro + i] = dr[i];
        if (S0) { S0[ro + i] = __float2half(1.f); S1[ro + i] = __float2half(dr[i]); }
    }
}

// ------- Chebyshev step, fp16 gather at 16B/lane: Tnext = 2*Ltilde*X - Tprev ----------
// One block per row; 256 threads x 8 fp16 columns each; one uint4 load per edge.
__global__ __launch_bounds__(256) void cheb_fp16(const __half* __restrict__ Xh,
                                                 const float* __restrict__ Tprev,
                                                 float* __restrict__ Tnext,
                                                 __half* __restrict__ slot,
                                                 const int* __restrict__ cnt,
                                                 const int* __restrict__ cols,
                                                 const float* __restrict__ vals,
                                                 const float* __restrict__ dr) {
    int i   = blockIdx.x;
    int col = threadIdx.x * 8;
    __shared__ int   scols[ELLW_];
    __shared__ float svals[ELLW_];
    if (threadIdx.x < ELLW_) {
        scols[threadIdx.x] = cols[i * ELLW_ + threadIdx.x];
        svals[threadIdx.x] = vals[i * ELLW_ + threadIdx.x];
    }
    __syncthreads();
    int n = cnt[i];
    float a0 = 0.f, a1 = 0.f, a2 = 0.f, a3 = 0.f,
          a4 = 0.f, a5 = 0.f, a6 = 0.f, a7 = 0.f;
    for (int e = 0; e < n; ++e) {
        int   c = scols[e];
        float v = svals[e];
        uint4 q = *(const uint4*)(Xh + (size_t)c * N_ + col);
        const __half2* h = (const __half2*)&q;
        float2 f0 = __half22float2(h[0]), f1 = __half22float2(h[1]);
        float2 f2 = __half22float2(h[2]), f3 = __half22float2(h[3]);
        a0 -= v * f0.x; a1 -= v * f0.y; a2 -= v * f1.x; a3 -= v * f1.y;
        a4 -= v * f2.x; a5 -= v * f2.y; a6 -= v * f3.x; a7 -= v * f3.y;
    }
    {   // diagonal term
        float d = dr[i];
        uint4 q = *(const uint4*)(Xh + (size_t)i * N_ + col);
        const __half2* h = (const __half2*)&q;
        float2 f0 = __half22float2(h[0]), f1 = __half22float2(h[1]);
        float2 f2 = __half22float2(h[2]), f3 = __half22float2(h[3]);
        a0 += d * f0.x; a1 += d * f0.y; a2 += d * f1.x; a3 += d * f1.y;
        a4 += d * f2.x; a5 += d * f2.y; a6 += d * f3.x; a7 += d * f3.y;
    }
    size_t po = (size_t)i * N_ + col;
    float4 p0 = *(const float4*)(Tprev + po);
    float4 p1 = *(const float4*)(Tprev + po + 4);
    float4 o0, o1;
    o0.x = 2.f * a0 - p0.x; o0.y = 2.f * a1 - p0.y;
    o0.z = 2.f * a2 - p0.z; o0.w = 2.f * a3 - p0.w;
    o1.x = 2.f * a4 - p1.x; o1.y = 2.f * a5 - p1.y;
    o1.z = 2.f * a6 - p1.z; o1.w = 2.f * a7 - p1.w;
    *(float4*)(Tnext + po)     = o0;
    *(float4*)(Tnext + po + 4) = o1;
    __half2 s0 = __floats2half2_rn(o0.x, o0.y);
    __half2 s1 = __floats2half2_rn(o0.z, o0.w);
    __half2 s2 = __floats2half2_rn(o1.x, o1.y);
    __half2 s3 = __floats2half2_rn(o1.z, o1.w);
    uint4 sq;
    sq.x = *(const unsigned int*)&s0; sq.y = *(const unsigned int*)&s1;
    sq.z = *(const unsigned int*)&s2; sq.w = *(const unsigned int*)&s3;
    *(uint4*)(slot + po) = sq;
}

// ---------------- legacy fp32-gather step (fallback when workspace is tiny) -------------
__global__ __launch_bounds__(256) void cheb_step(const float* __restrict__ X,
                                                 const float* __restrict__ Tprev,
                                                 float* __restrict__ Tnext,
                                                 __half* __restrict__ slot,
                                                 const int* __restrict__ cnt,
                                                 const int* __restrict__ cols,
                                                 const float* __restrict__ vals,
                                                 const float* __restrict__ dr) {
    int i = blockIdx.x;
    int col = blockIdx.y * 1024 + threadIdx.x * 4;
    __shared__ int   scols[ELLW_];
    __shared__ float svals[ELLW_];
    int n = cnt[i];
    if (threadIdx.x < ELLW_) {
        scols[threadIdx.x] = cols[i * ELLW_ + threadIdx.x];
        svals[threadIdx.x] = vals[i * ELLW_ + threadIdx.x];
    }
    __syncthreads();
    float4 acc = {0, 0, 0, 0};
    for (int e = 0; e < n; ++e) {
        const float4 xv = *(const float4*)(X + (size_t)scols[e] * N_ + col);
        float v = svals[e];
        acc.x -= v * xv.x; acc.y -= v * xv.y; acc.z -= v * xv.z; acc.w -= v * xv.w;
    }
    float4 xs = *(const float4*)(X + (size_t)i * N_ + col);
    float d = dr[i];
    acc.x += d * xs.x; acc.y += d * xs.y; acc.z += d * xs.z; acc.w += d * xs.w;
    float4 tp = *(const float4*)(Tprev + (size_t)i * N_ + col);
    float4 o;
    o.x = 2.f * acc.x - tp.x; o.y = 2.f * acc.y - tp.y;
    o.z = 2.f * acc.z - tp.z; o.w = 2.f * acc.w - tp.w;
    *(float4*)(Tnext + (size_t)i * N_ + col) = o;
    if (slot) {
        __half2* sp = (__half2*)(slot + (size_t)i * N_ + col);
        sp[0] = __floats2half2_rn(o.x, o.y);
        sp[1] = __floats2half2_rn(o.z, o.w);
    }
}

// ---------------- group reduction:  G_j += sum_s b_{j,k0+s} * T_slot_s ----------------
// 8 elems/thread, 16B slot loads. On the final pass (Gbout != null) write bf16 only.
__global__ __launch_bounds__(256) void reduce_half(const __half* __restrict__ slots, int nslot,
                                                   const float* __restrict__ coefs, int k0, int initG,
                                                   float* __restrict__ G,
                                                   u16* __restrict__ Gbout) {
    const size_t NSQ = (size_t)N_ * N_;
    size_t idx = ((size_t)blockIdx.x * 256 + threadIdx.x) * 8;
    __shared__ float sc[J_ * 64];
    for (int x = threadIdx.x; x < J_ * nslot; x += 256) {
        int j = x / nslot, s = x - j * nslot;
        sc[j * 64 + s] = coefs[j * M_ + k0 + s];
    }
    __syncthreads();
    float g[J_][8];
#pragma unroll
    for (int j = 0; j < J_; ++j) {
        if (initG) {
#pragma unroll
            for (int r = 0; r < 8; ++r) g[j][r] = 0.f;
        } else {
            float4 q0 = *(const float4*)(G + (size_t)j * NSQ + idx);
            float4 q1 = *(const float4*)(G + (size_t)j * NSQ + idx + 4);
            g[j][0] = q0.x; g[j][1] = q0.y; g[j][2] = q0.z; g[j][3] = q0.w;
            g[j][4] = q1.x; g[j][5] = q1.y; g[j][6] = q1.z; g[j][7] = q1.w;
        }
    }
    for (int s = 0; s < nslot; ++s) {
        uint4 q = *(const uint4*)(slots + (size_t)s * NSQ + idx);
        const __half2* h = (const __half2*)&q;
        float2 f0 = __half22float2(h[0]), f1 = __half22float2(h[1]);
        float2 f2 = __half22float2(h[2]), f3 = __half22float2(h[3]);
        float f[8] = {f0.x, f0.y, f1.x, f1.y, f2.x, f2.y, f3.x, f3.y};
#pragma unroll
        for (int j = 0; j < J_; ++j) {
            float c = sc[j * 64 + s];
#pragma unroll
            for (int r = 0; r < 8; ++r) g[j][r] += c * f[r];
        }
    }
    if (Gbout) {
#pragma unroll
        for (int j = 0; j < J_; ++j) {
            ushort4 o0, o1;
            o0.x = f2bf(g[j][0]); o0.y = f2bf(g[j][1]);
            o0.z = f2bf(g[j][2]); o0.w = f2bf(g[j][3]);
            o1.x = f2bf(g[j][4]); o1.y = f2bf(g[j][5]);
            o1.z = f2bf(g[j][6]); o1.w = f2bf(g[j][7]);
            *(ushort4*)(Gbout + (size_t)j * NSQ + idx)     = o0;
            *(ushort4*)(Gbout + (size_t)j * NSQ + idx + 4) = o1;
        }
    } else {
#pragma unroll
        for (int j = 0; j < J_; ++j) {
            *(float4*)(G + (size_t)j * NSQ + idx) =
                float4{g[j][0], g[j][1], g[j][2], g[j][3]};
            *(float4*)(G + (size_t)j * NSQ + idx + 4) =
                float4{g[j][4], g[j][5], g[j][6], g[j][7]};
        }
    }
}

__global__ __launch_bounds__(256) void reduce_f32(const float* __restrict__ T,
                                                  const float* __restrict__ coefs, int k, int initG,
                                                  float* __restrict__ G) {
    const size_t NSQ = (size_t)N_ * N_;
    size_t idx = ((size_t)blockIdx.x * 256 + threadIdx.x) * 4;
    float4 tv = *(const float4*)(T + idx);
#pragma unroll
    for (int j = 0; j < J_; ++j) {
        float c = coefs[j * M_ + k];
        float* gp = G + (size_t)j * NSQ + idx;
        float4 g = initG ? float4{0, 0, 0, 0} : *(float4*)gp;
        g.x += c * tv.x; g.y += c * tv.y; g.z += c * tv.z; g.w += c * tv.w;
        *(float4*)gp = g;
    }
}

// ---------------- fp32 -> bf16 convert ----------------
__global__ __launch_bounds__(256) void convert_bf16(const float* __restrict__ src,
                                                    u16* __restrict__ dst) {
    size_t i4 = ((size_t)blockIdx.x * 256 + threadIdx.x) * 4;
    float4 v = *(const float4*)(src + i4);
    ushort4 o;
    o.x = f2bf(v.x); o.y = f2bf(v.y); o.z = f2bf(v.z); o.w = f2bf(v.w);
    *(ushort4*)(dst + i4) = o;
}

// ---------------- MFMA bf16 GEMM with fused |.| + column-sum epilogue ----------------
template <int MODE>
__global__ __launch_bounds__(256) void mfma_gemm(const u16* __restrict__ A,
                                                 const u16* __restrict__ B,
                                                 u16* __restrict__ Uout,
                                                 float* __restrict__ colsum) {
    constexpr int LDK = 72;
    constexpr int NB  = (MODE == 0) ? 256 : 2048;
    __shared__ u16 As[128 * LDK];
    __shared__ u16 Bs[128 * LDK];
    int tid = threadIdx.x;
    int w = tid >> 6, lane = tid & 63;
    int wr = w >> 1, wc = w & 1;
    int gm0 = blockIdx.y * 128, n0 = blockIdx.x * 128;
    f32x4 acc[4][4];
#pragma unroll
    for (int mf = 0; mf < 4; ++mf)
#pragma unroll
        for (int nf = 0; nf < 4; ++nf) acc[mf][nf] = (f32x4){0.f, 0.f, 0.f, 0.f};

    int r = tid >> 1, h = tid & 1;
    int kk = tid >> 2, seg = tid & 3;
    for (int k0 = 0; k0 < 2048; k0 += 64) {
        const u16* ap = A + (size_t)(gm0 + r) * 2048 + k0 + h * 32;
        u16* as = As + r * LDK + h * 32;
        *(uint4*)(as + 0)  = *(const uint4*)(ap + 0);
        *(uint4*)(as + 8)  = *(const uint4*)(ap + 8);
        *(uint4*)(as + 16) = *(const uint4*)(ap + 16);
        *(uint4*)(as + 24) = *(const uint4*)(ap + 24);
        const u16* bp = B + (size_t)(k0 + kk) * NB + n0 + seg * 32;
        uint4 q0 = *(const uint4*)(bp + 0);
        uint4 q1 = *(const uint4*)(bp + 8);
        uint4 q2 = *(const uint4*)(bp + 16);
        uint4 q3 = *(const uint4*)(bp + 24);
        u16* bs = Bs + (seg * 32) * LDK + kk;
#define WR8(Q, base) \
        bs[(base + 0) * LDK] = (u16)(Q.x);       bs[(base + 1) * LDK] = (u16)(Q.x >> 16); \
        bs[(base + 2) * LDK] = (u16)(Q.y);       bs[(base + 3) * LDK] = (u16)(Q.y >> 16); \
        bs[(base + 4) * LDK] = (u16)(Q.z);       bs[(base + 5) * LDK] = (u16)(Q.z >> 16); \
        bs[(base + 6) * LDK] = (u16)(Q.w);       bs[(base + 7) * LDK] = (u16)(Q.w >> 16);
        WR8(q0, 0) WR8(q1, 8) WR8(q2, 16) WR8(q3, 24)
#undef WR8
        __syncthreads();
#pragma unroll
        for (int s = 0; s < 2; ++s) {
            int krd = s * 32 + (lane >> 4) * 8;
            bf16x8 af[4], bfv[4];
#pragma unroll
            for (int mf = 0; mf < 4; ++mf)
                af[mf] = *(const bf16x8*)(As + (wr * 64 + mf * 16 + (lane & 15)) * LDK + krd);
#pragma unroll
            for (int nf = 0; nf < 4; ++nf)
                bfv[nf] = *(const bf16x8*)(Bs + (wc * 64 + nf * 16 + (lane & 15)) * LDK + krd);
#pragma unroll
            for (int mf = 0; mf < 4; ++mf)
#pragma unroll
                for (int nf = 0; nf < 4; ++nf)
                    acc[mf][nf] = __builtin_amdgcn_mfma_f32_16x16x32_bf16(
                        af[mf], bfv[nf], acc[mf][nf], 0, 0, 0);
        }
        __syncthreads();
    }
    int j = gm0 >> 11;
#pragma unroll
    for (int nf = 0; nf < 4; ++nf) {
        float cs = 0.f;
#pragma unroll
        for (int mf = 0; mf < 4; ++mf) {
#pragma unroll
            for (int rr = 0; rr < 4; ++rr) {
                float val = fabsf(acc[mf][nf][rr]);
                cs += val;
                if (MODE == 0) {
                    int gm = gm0 + wr * 64 + mf * 16 + (lane >> 4) * 4 + rr;
                    int i = gm & (N_ - 1);
                    int d = n0 + wc * 64 + nf * 16 + (lane & 15);
                    Uout[(size_t)i * 2048 + j * 256 + d] = f2bf(val);
                }
            }
        }
        cs += __shfl_xor(cs, 16);
        cs += __shfl_xor(cs, 32);
        if ((lane >> 4) == 0) {
            int colg = n0 + wc * 64 + nf * 16 + lane;
            if (MODE == 0) atomicAdd(&colsum[j * 256 + colg], cs);
            else atomicAdd(&colsum[(((colg >> 8) * 8 + j) << 8) + (colg & 255)], cs);
        }
    }
}

__global__ __launch_bounds__(256) void fmean_kernel(const float* __restrict__ f, float* __restrict__ out) {
    int d = threadIdx.x;
    float s = 0.f;
    for (int n = 0; n < N_; ++n) s += f[(size_t)n * DF_ + d];
    out[d] = s * (1.f / N_);
}

__global__ __launch_bounds__(256) void finalize_kernel(const float* __restrict__ sum1,
                                                       const float* __restrict__ sum2,
                                                       float* __restrict__ out) {
    int idx = blockIdx.x * 256 + threadIdx.x;
    if (idx < 2048)  out[256 + idx]  = sum1[idx] * (1.f / N_);
    if (idx < 16384) out[2304 + idx] = sum2[idx] * (1.f / N_);
}

// ---------------- host orchestration ----------------
extern "C" void kernel_launch(void* const* d_in, const int* in_sizes, int n_in,
                              void* d_out, int out_size, void* d_ws, size_t ws_size,
                              hipStream_t stream) {
    (void)in_sizes; (void)n_in;
    const float* W = (const float*)d_in[0];
    const float* f = (const float*)d_in[1];
    float* out = (float*)d_out;
    char* base = (char*)d_ws;
    size_t off = 0;
    auto take = [&](size_t bytes) -> char* {
        off = (off + 255) & ~(size_t)255;
        char* p = base + off; off += bytes; return p;
    };
    const size_t NSQ = (size_t)N_ * N_;
    float* dh    = (float*)take((size_t)N_ * 4);
    float* dr    = (float*)take((size_t)N_ * 4);
    int*   cnt   = (int*)take((size_t)N_ * 4);
    int*   cols  = (int*)take((size_t)N_ * ELLW_ * 4);
    float* vals  = (float*)take((size_t)N_ * ELLW_ * 4);
    float* coefs = (float*)take((size_t)J_ * M_ * 4);
    float* sum1  = (float*)take(2048 * 4);
    float* sum2  = (float*)take(16384 * 4);
    float* T0 = (float*)take(NSQ * 4);
    float* T1 = (float*)take(NSQ * 4);
    float* T2 = (float*)take(NSQ * 4);
    float* G  = (float*)take(NSQ * 4 * J_);
    u16*   Gb  = (u16*)take(NSQ * 2 * J_);
    u16*   U1b = (u16*)take((size_t)N_ * 2048 * 2);
    u16*   fb  = (u16*)take((size_t)N_ * DF_ * 2);
    off = (off + 255) & ~(size_t)255;
    if (ws_size < off) {
        hipMemsetAsync(d_out, 0, (size_t)out_size * 4, stream);
        return;
    }
    const size_t slotBytes = NSQ * 2;
    long long rem = (long long)ws_size - (long long)off;
    int g = (int)(rem / (long long)slotBytes);
    if (g > 64) g = 64;
    __half* slots = (__half*)(base + off);
    bool f16path = g >= 3;

    deg_kernel<<<N_, 256, 0, stream>>>(W, dh, dr);
    ell_kernel<<<N_, 64, 0, stream>>>(W, dh, cnt, cols, vals);
    coef_kernel<<<1, 256, 0, stream>>>(coefs);
    hipMemsetAsync(sum1, 0, 2048 * 4, stream);
    hipMemsetAsync(sum2, 0, 16384 * 4, stream);
    init_T<<<N_, 256, 0, stream>>>(T0, T1,
                                   f16path ? slots : (__half*)nullptr,
                                   f16path ? slots + NSQ : (__half*)nullptr,
                                   cnt, cols, vals, dr);
    float* Tb[3] = {T0, T1, T2};
    if (f16path) {
        __half* slotX = slots + NSQ;   // fp16 copy of T1
        int group_start = 0;
        for (int k = 2; k < M_; ++k) {
            __half* slotW = slots + (size_t)(k - group_start) * NSQ;
            cheb_fp16<<<N_, 256, 0, stream>>>(
                slotX, Tb[(k - 2) % 3], Tb[k % 3], slotW, cnt, cols, vals, dr);
            slotX = slotW;
            if (k - group_start + 1 == g || k == M_ - 1) {
                int nslot = k - group_start + 1;
                bool last = (k == M_ - 1);
                reduce_half<<<2048, 256, 0, stream>>>(slots, nslot, coefs, group_start,
                                                      group_start == 0 ? 1 : 0, G,
                                                      last ? Gb : (u16*)nullptr);
                group_start = k + 1;
            }
        }
    } else {
        reduce_f32<<<4096, 256, 0, stream>>>(T0, coefs, 0, 1, G);
        reduce_f32<<<4096, 256, 0, stream>>>(T1, coefs, 1, 0, G);
        for (int k = 2; k < M_; ++k) {
            cheb_step<<<dim3(N_, 2), 256, 0, stream>>>(
                Tb[(k - 1) % 3], Tb[(k - 2) % 3], Tb[k % 3],
                (__half*)nullptr, cnt, cols, vals, dr);
            reduce_f32<<<4096, 256, 0, stream>>>(Tb[k % 3], coefs, k, 0, G);
        }
        convert_bf16<<<32768, 256, 0, stream>>>(G, Gb);
    }
    convert_bf16<<<512, 256, 0, stream>>>(f, fb);
    mfma_gemm<0><<<dim3(2, 128), 256, 0, stream>>>(Gb, fb, U1b, sum1);
    mfma_gemm<1><<<dim3(16, 128), 256, 0, stream>>>(Gb, U1b, (u16*)nullptr, sum2);
    fmean_kernel<<<1, 256, 0, stream>>>(f, out);
    finalize_kernel<<<64, 256, 0, stream>>>(sum1, sum2, out);
}

// Round 4
// 6167.531 us; speedup vs baseline: 3.3317x; 3.3317x over previous
//
#include <hip/hip_runtime.h>
#include <hip/hip_fp16.h>
#include <math.h>

// ---------------- constants ----------------
constexpr int   N_   = 2048;
constexpr int   DF_  = 256;
constexpr int   J_   = 8;
constexpr int   ELLW_= 64;
constexpr int   M_   = 256;          // Chebyshev terms (degree 255)
constexpr float H_   = 1.01f;        // domain half-width  ([-0.01, 2.01])
constexpr float C0_  = 1.0f;         // domain center
constexpr float AF_  = 0.34657359027997264f;   // A = 3*ln(2)/6
constexpr float PI_F = 3.14159265358979323846f;

typedef _Float16 f16x8 __attribute__((ext_vector_type(8)));
typedef __attribute__((ext_vector_type(4))) float f32x4;
using u16 = unsigned short;

// ---------------- filter functions ----------------
__device__ __forceinline__ float g_hat_f(float x) {
    float val = 0.5f + 0.5f * cosf(2.f * PI_F * (x / AF_ + 0.5f));
    return (x <= 0.f && x > -AF_) ? val : 0.f;
}
__device__ __forceinline__ float wavelet_f(float lamb, int j) {
    float lmin = expf(AF_ * ((j - 1) / 3.0f - 1.0f));
    float lam  = fmaxf(lamb, lmin);
    return g_hat_f(logf(lam) - AF_ * (j - 1) / 3.0f);
}
__device__ __forceinline__ float filter_eval(float lamb, int jf) {
    if (jf == 0) {
        float g3 = 0.f;
        for (int j = 2; j <= 8; ++j) { float w = wavelet_f(lamb, j); g3 += w * w; }
        return sqrtf(fmaxf(1.5f - g3, 0.f));
    }
    return wavelet_f(lamb, jf + 1);
}

// ---------------- setup kernels ----------------
__global__ __launch_bounds__(256) void deg_kernel(const float* __restrict__ W,
                                                  float* __restrict__ dh,
                                                  float* __restrict__ dr) {
    int i = blockIdx.x, t = threadIdx.x;
    const float4* row = (const float4*)(W + (size_t)i * N_);
    float s = 0.f;
    for (int c = t; c < N_ / 4; c += 256) { float4 v = row[c]; s += v.x + v.y + v.z + v.w; }
    __shared__ float red[256];
    red[t] = s; __syncthreads();
    for (int o = 128; o; o >>= 1) { if (t < o) red[t] += red[t + o]; __syncthreads(); }
    if (t == 0) {
        float deg = red[0];
        float dhi = 1.f / sqrtf(fmaxf(deg, 1.f));
        dh[i] = dhi;
        dr[i] = (dhi * dhi * deg - C0_) / H_;
    }
}

// ELL build: all 64 entries pre-filled with (col=i, val=0) pads; cnt rounded up to mult of 8.
__global__ __launch_bounds__(64) void ell_kernel(const float* __restrict__ W,
                                                 const float* __restrict__ dh,
                                                 int* __restrict__ cnt,
                                                 int* __restrict__ cols,
                                                 float* __restrict__ vals) {
    int i = blockIdx.x, lane = threadIdx.x;
    cols[i * ELLW_ + lane] = i;            // pad defaults
    vals[i * ELLW_ + lane] = 0.f;
    __syncthreads();
    const float* row = W + (size_t)i * N_;
    unsigned long long lt = (1ull << lane) - 1ull;
    int base = 0;
    float dhi = dh[i];
    for (int c = 0; c < N_; c += 64) {
        float v = row[c + lane];
        unsigned long long m = __ballot(v != 0.f);
        if (v != 0.f) {
            int pos = base + __popcll(m & lt);
            if (pos < ELLW_) {
                cols[i * ELLW_ + pos] = c + lane;
                vals[i * ELLW_ + pos] = dhi * dh[c + lane] / H_;
            }
        }
        base += __popcll(m);
    }
    if (lane == 0) {
        int n = base < ELLW_ ? base : ELLW_;
        cnt[i] = (n + 7) & ~7;             // padded count (pads are no-ops)
    }
}

__global__ __launch_bounds__(256) void coef_kernel(float* __restrict__ coefs) {
    __shared__ float fv[J_][M_];
    int t = threadIdx.x;
    float theta = PI_F * (t + 0.5f) / M_;
    float lam = C0_ + H_ * cosf(theta);
    for (int j = 0; j < J_; ++j) fv[j][t] = filter_eval(lam, j);
    __syncthreads();
    for (int j = 0; j < J_; ++j) {
        float s = 0.f;
        for (int i = 0; i < M_; ++i)
            s += fv[j][i] * cosf(PI_F * t * (i + 0.5f) / M_);
        coefs[j * M_ + t] = s * ((t == 0 ? 1.f : 2.f) / M_);
    }
}

// slot0 = I (fp16), slot1 = scaled L-tilde (fp16)
__global__ __launch_bounds__(256) void init_slots(__half* __restrict__ S0, __half* __restrict__ S1,
                                                  const int* __restrict__ cnt, const int* __restrict__ cols,
                                                  const float* __restrict__ vals, const float* __restrict__ dr) {
    int i = blockIdx.x, t = threadIdx.x;
    size_t ro = (size_t)i * N_;
    for (int c = t * 8; c < N_; c += 2048) {
        *(uint4*)(S0 + ro + c) = uint4{0, 0, 0, 0};
        *(uint4*)(S1 + ro + c) = uint4{0, 0, 0, 0};
    }
    __syncthreads();
    int n = cnt[i];
    if (t < n) {
        int c = cols[i * ELLW_ + t];
        float v = -vals[i * ELLW_ + t];
        if (v != 0.f) S1[ro + c] = __float2half(v);   // skip pads (col=i, val=0)
    }
    __syncthreads();
    if (t == 0) {
        S0[ro + i] = __float2half(1.f);
        S1[ro + i] = __float2half(dr[i]);
    }
}

// ------- Chebyshev step, full fp16 state: S_k = 2*Ltilde*S_{k-1} - S_{k-2} ----------
// One block per row; 256 threads x 8 fp16 cols; edge loop unrolled by 8 (padded).
__global__ __launch_bounds__(256) void cheb_fp16(const __half* __restrict__ X,
                                                 const __half* __restrict__ Tprev,
                                                 __half* __restrict__ Tnext,
                                                 const int* __restrict__ cnt,
                                                 const int* __restrict__ cols,
                                                 const float* __restrict__ vals,
                                                 const float* __restrict__ dr) {
    int i   = blockIdx.x;
    int col = threadIdx.x * 8;
    __shared__ int   scols[ELLW_];
    __shared__ float svals[ELLW_];
    if (threadIdx.x < ELLW_) {
        scols[threadIdx.x] = cols[i * ELLW_ + threadIdx.x];
        svals[threadIdx.x] = vals[i * ELLW_ + threadIdx.x];
    }
    __syncthreads();
    int n = cnt[i];                          // multiple of 8 (or 0)
    float a[8] = {0, 0, 0, 0, 0, 0, 0, 0};
    for (int e0 = 0; e0 < n; e0 += 8) {
        uint4 q[8];
        float v[8];
#pragma unroll
        for (int u = 0; u < 8; ++u) {
            int c = scols[e0 + u];
            v[u] = svals[e0 + u];
            q[u] = *(const uint4*)(X + (size_t)c * N_ + col);
        }
#pragma unroll
        for (int u = 0; u < 8; ++u) {
            const __half2* h = (const __half2*)&q[u];
            float2 f0 = __half22float2(h[0]), f1 = __half22float2(h[1]);
            float2 f2 = __half22float2(h[2]), f3 = __half22float2(h[3]);
            a[0] -= v[u] * f0.x; a[1] -= v[u] * f0.y;
            a[2] -= v[u] * f1.x; a[3] -= v[u] * f1.y;
            a[4] -= v[u] * f2.x; a[5] -= v[u] * f2.y;
            a[6] -= v[u] * f3.x; a[7] -= v[u] * f3.y;
        }
    }
    size_t po = (size_t)i * N_ + col;
    {   // diagonal term
        float d = dr[i];
        uint4 q = *(const uint4*)(X + po);
        const __half2* h = (const __half2*)&q;
        float2 f0 = __half22float2(h[0]), f1 = __half22float2(h[1]);
        float2 f2 = __half22float2(h[2]), f3 = __half22float2(h[3]);
        a[0] += d * f0.x; a[1] += d * f0.y; a[2] += d * f1.x; a[3] += d * f1.y;
        a[4] += d * f2.x; a[5] += d * f2.y; a[6] += d * f3.x; a[7] += d * f3.y;
    }
    uint4 qp = *(const uint4*)(Tprev + po);
    const __half2* hp = (const __half2*)&qp;
    float2 p0 = __half22float2(hp[0]), p1 = __half22float2(hp[1]);
    float2 p2 = __half22float2(hp[2]), p3 = __half22float2(hp[3]);
    __half2 s0 = __floats2half2_rn(2.f * a[0] - p0.x, 2.f * a[1] - p0.y);
    __half2 s1 = __floats2half2_rn(2.f * a[2] - p1.x, 2.f * a[3] - p1.y);
    __half2 s2 = __floats2half2_rn(2.f * a[4] - p2.x, 2.f * a[5] - p2.y);
    __half2 s3 = __floats2half2_rn(2.f * a[6] - p3.x, 2.f * a[7] - p3.y);
    uint4 sq;
    sq.x = *(const unsigned int*)&s0; sq.y = *(const unsigned int*)&s1;
    sq.z = *(const unsigned int*)&s2; sq.w = *(const unsigned int*)&s3;
    *(uint4*)(Tnext + po) = sq;
}

// ---------------- group reduction: Gh_j += sum_{k in [k0,k0+nslot)} b_{jk} * slot(k%g) -------
__global__ __launch_bounds__(256) void reduce_half(const __half* __restrict__ slots,
                                                   int g, int k0, int nslot, int initG,
                                                   const float* __restrict__ coefs,
                                                   __half* __restrict__ Gh) {
    const size_t NSQ = (size_t)N_ * N_;
    size_t idx = ((size_t)blockIdx.x * 256 + threadIdx.x) * 8;
    __shared__ float sc[J_ * 64];
    for (int x = threadIdx.x; x < J_ * nslot; x += 256) {
        int j = x / nslot, s = x - j * nslot;
        sc[j * 64 + s] = coefs[j * M_ + k0 + s];
    }
    __syncthreads();
    float acc[J_][8];
#pragma unroll
    for (int j = 0; j < J_; ++j) {
        if (initG) {
#pragma unroll
            for (int r = 0; r < 8; ++r) acc[j][r] = 0.f;
        } else {
            uint4 q = *(const uint4*)(Gh + (size_t)j * NSQ + idx);
            const __half2* h = (const __half2*)&q;
            float2 f0 = __half22float2(h[0]), f1 = __half22float2(h[1]);
            float2 f2 = __half22float2(h[2]), f3 = __half22float2(h[3]);
            acc[j][0] = f0.x; acc[j][1] = f0.y; acc[j][2] = f1.x; acc[j][3] = f1.y;
            acc[j][4] = f2.x; acc[j][5] = f2.y; acc[j][6] = f3.x; acc[j][7] = f3.y;
        }
    }
    for (int s = 0; s < nslot; ++s) {
        int slot = (k0 + s) % g;
        uint4 q = *(const uint4*)(slots + (size_t)slot * NSQ + idx);
        const __half2* h = (const __half2*)&q;
        float2 f0 = __half22float2(h[0]), f1 = __half22float2(h[1]);
        float2 f2 = __half22float2(h[2]), f3 = __half22float2(h[3]);
        float f[8] = {f0.x, f0.y, f1.x, f1.y, f2.x, f2.y, f3.x, f3.y};
#pragma unroll
        for (int j = 0; j < J_; ++j) {
            float c = sc[j * 64 + s];
#pragma unroll
            for (int r = 0; r < 8; ++r) acc[j][r] += c * f[r];
        }
    }
#pragma unroll
    for (int j = 0; j < J_; ++j) {
        __half2 o0 = __floats2half2_rn(acc[j][0], acc[j][1]);
        __half2 o1 = __floats2half2_rn(acc[j][2], acc[j][3]);
        __half2 o2 = __floats2half2_rn(acc[j][4], acc[j][5]);
        __half2 o3 = __floats2half2_rn(acc[j][6], acc[j][7]);
        uint4 o;
        o.x = *(const unsigned int*)&o0; o.y = *(const unsigned int*)&o1;
        o.z = *(const unsigned int*)&o2; o.w = *(const unsigned int*)&o3;
        *(uint4*)(Gh + (size_t)j * NSQ + idx) = o;
    }
}

// ---------------- f32 -> f16 convert ----------------
__global__ __launch_bounds__(256) void convert_f16(const float* __restrict__ src,
                                                   __half* __restrict__ dst) {
    size_t i4 = ((size_t)blockIdx.x * 256 + threadIdx.x) * 4;
    float4 v = *(const float4*)(src + i4);
    __half2 h0 = __floats2half2_rn(v.x, v.y);
    __half2 h1 = __floats2half2_rn(v.z, v.w);
    uint2 o;
    o.x = *(const unsigned int*)&h0; o.y = *(const unsigned int*)&h1;
    *(uint2*)(dst + i4) = o;
}

// ---------------- MFMA fp16 GEMM with fused |.| + column-sum epilogue ----------------
// C = Gh[16384 x 2048] * B.  MODE 0: B = fh (2048 x 256), store U1h fp16 [i][j*256+d],
// colsum1[j*256+d].  MODE 1: B = U1h (2048 x 2048), colsum2[(b*8+j)*256+d].
template <int MODE>
__global__ __launch_bounds__(256) void mfma_gemm(const __half* __restrict__ A,
                                                 const __half* __restrict__ B,
                                                 __half* __restrict__ Uout,
                                                 float* __restrict__ colsum) {
    constexpr int LDK = 72;
    constexpr int NB  = (MODE == 0) ? 256 : 2048;
    __shared__ u16 As[128 * LDK];
    __shared__ u16 Bs[128 * LDK];
    int tid = threadIdx.x;
    int w = tid >> 6, lane = tid & 63;
    int wr = w >> 1, wc = w & 1;
    int gm0 = blockIdx.y * 128, n0 = blockIdx.x * 128;
    f32x4 acc[4][4];
#pragma unroll
    for (int mf = 0; mf < 4; ++mf)
#pragma unroll
        for (int nf = 0; nf < 4; ++nf) acc[mf][nf] = (f32x4){0.f, 0.f, 0.f, 0.f};

    int r = tid >> 1, h = tid & 1;
    int kk = tid >> 2, seg = tid & 3;
    for (int k0 = 0; k0 < 2048; k0 += 64) {
        const u16* ap = (const u16*)A + (size_t)(gm0 + r) * 2048 + k0 + h * 32;
        u16* as = As + r * LDK + h * 32;
        *(uint4*)(as + 0)  = *(const uint4*)(ap + 0);
        *(uint4*)(as + 8)  = *(const uint4*)(ap + 8);
        *(uint4*)(as + 16) = *(const uint4*)(ap + 16);
        *(uint4*)(as + 24) = *(const uint4*)(ap + 24);
        const u16* bp = (const u16*)B + (size_t)(k0 + kk) * NB + n0 + seg * 32;
        uint4 q0 = *(const uint4*)(bp + 0);
        uint4 q1 = *(const uint4*)(bp + 8);
        uint4 q2 = *(const uint4*)(bp + 16);
        uint4 q3 = *(const uint4*)(bp + 24);
        u16* bs = Bs + (seg * 32) * LDK + kk;
#define WR8(Q, base) \
        bs[(base + 0) * LDK] = (u16)(Q.x);       bs[(base + 1) * LDK] = (u16)(Q.x >> 16); \
        bs[(base + 2) * LDK] = (u16)(Q.y);       bs[(base + 3) * LDK] = (u16)(Q.y >> 16); \
        bs[(base + 4) * LDK] = (u16)(Q.z);       bs[(base + 5) * LDK] = (u16)(Q.z >> 16); \
        bs[(base + 6) * LDK] = (u16)(Q.w);       bs[(base + 7) * LDK] = (u16)(Q.w >> 16);
        WR8(q0, 0) WR8(q1, 8) WR8(q2, 16) WR8(q3, 24)
#undef WR8
        __syncthreads();
#pragma unroll
        for (int s = 0; s < 2; ++s) {
            int krd = s * 32 + (lane >> 4) * 8;
            f16x8 af[4], bfv[4];
#pragma unroll
            for (int mf = 0; mf < 4; ++mf)
                af[mf] = *(const f16x8*)(As + (wr * 64 + mf * 16 + (lane & 15)) * LDK + krd);
#pragma unroll
            for (int nf = 0; nf < 4; ++nf)
                bfv[nf] = *(const f16x8*)(Bs + (wc * 64 + nf * 16 + (lane & 15)) * LDK + krd);
#pragma unroll
            for (int mf = 0; mf < 4; ++mf)
#pragma unroll
                for (int nf = 0; nf < 4; ++nf)
                    acc[mf][nf] = __builtin_amdgcn_mfma_f32_16x16x32_f16(
                        af[mf], bfv[nf], acc[mf][nf], 0, 0, 0);
        }
        __syncthreads();
    }
    int j = gm0 >> 11;
#pragma unroll
    for (int nf = 0; nf < 4; ++nf) {
        float cs = 0.f;
#pragma unroll
        for (int mf = 0; mf < 4; ++mf) {
#pragma unroll
            for (int rr = 0; rr < 4; ++rr) {
                float val = fabsf(acc[mf][nf][rr]);
                cs += val;
                if (MODE == 0) {
                    int gm = gm0 + wr * 64 + mf * 16 + (lane >> 4) * 4 + rr;
                    int i = gm & (N_ - 1);
                    int d = n0 + wc * 64 + nf * 16 + (lane & 15);
                    Uout[(size_t)i * 2048 + j * 256 + d] = __float2half(val);
                }
            }
        }
        cs += __shfl_xor(cs, 16);
        cs += __shfl_xor(cs, 32);
        if ((lane >> 4) == 0) {
            int colg = n0 + wc * 64 + nf * 16 + lane;
            if (MODE == 0) atomicAdd(&colsum[j * 256 + colg], cs);
            else atomicAdd(&colsum[(((colg >> 8) * 8 + j) << 8) + (colg & 255)], cs);
        }
    }
}

__global__ __launch_bounds__(256) void fmean_kernel(const float* __restrict__ f, float* __restrict__ out) {
    int d = threadIdx.x;
    float s = 0.f;
    for (int n = 0; n < N_; ++n) s += f[(size_t)n * DF_ + d];
    out[d] = s * (1.f / N_);
}

__global__ __launch_bounds__(256) void finalize_kernel(const float* __restrict__ sum1,
                                                       const float* __restrict__ sum2,
                                                       float* __restrict__ out) {
    int idx = blockIdx.x * 256 + threadIdx.x;
    if (idx < 2048)  out[256 + idx]  = sum1[idx] * (1.f / N_);
    if (idx < 16384) out[2304 + idx] = sum2[idx] * (1.f / N_);
}

// ---------------- host orchestration ----------------
extern "C" void kernel_launch(void* const* d_in, const int* in_sizes, int n_in,
                              void* d_out, int out_size, void* d_ws, size_t ws_size,
                              hipStream_t stream) {
    (void)in_sizes; (void)n_in;
    const float* W = (const float*)d_in[0];
    const float* f = (const float*)d_in[1];
    float* out = (float*)d_out;
    char* base = (char*)d_ws;
    size_t off = 0;
    auto take = [&](size_t bytes) -> char* {
        off = (off + 255) & ~(size_t)255;
        char* p = base + off; off += bytes; return p;
    };
    const size_t NSQ = (size_t)N_ * N_;
    float*  dh    = (float*)take((size_t)N_ * 4);
    float*  dr    = (float*)take((size_t)N_ * 4);
    int*    cnt   = (int*)take((size_t)N_ * 4);
    int*    cols  = (int*)take((size_t)N_ * ELLW_ * 4);
    float*  vals  = (float*)take((size_t)N_ * ELLW_ * 4);
    float*  coefs = (float*)take((size_t)J_ * M_ * 4);
    float*  sum1  = (float*)take(2048 * 4);
    float*  sum2  = (float*)take(16384 * 4);
    __half* Gh    = (__half*)take(NSQ * 2 * J_);                 //  67.1 MB
    __half* U1h   = (__half*)take((size_t)N_ * 2048 * 2);        //   8.4 MB
    __half* fh    = (__half*)take((size_t)N_ * DF_ * 2);         //   1.0 MB
    off = (off + 255) & ~(size_t)255;
    const size_t slotBytes = NSQ * 2;
    long long rem = (long long)ws_size - (long long)off;
    int g = (int)(rem / (long long)slotBytes);
    if (g > 20) g = 20;
    if (g < 3) {                       // workspace too small — cannot run
        hipMemsetAsync(d_out, 0, (size_t)out_size * 4, stream);
        return;
    }
    __half* slots = (__half*)take((size_t)g * slotBytes);

    deg_kernel<<<N_, 256, 0, stream>>>(W, dh, dr);
    ell_kernel<<<N_, 64, 0, stream>>>(W, dh, cnt, cols, vals);
    coef_kernel<<<1, 256, 0, stream>>>(coefs);
    hipMemsetAsync(sum1, 0, 2048 * 4, stream);
    hipMemsetAsync(sum2, 0, 16384 * 4, stream);
    init_slots<<<N_, 256, 0, stream>>>(slots, slots + NSQ, cnt, cols, vals, dr);

    int k0 = 0;                        // start of current un-reduced group
    for (int k = 2; k < M_; ++k) {
        cheb_fp16<<<N_, 256, 0, stream>>>(
            slots + (size_t)((k - 1) % g) * NSQ,
            slots + (size_t)((k - 2) % g) * NSQ,
            slots + (size_t)(k % g) * NSQ,
            cnt, cols, vals, dr);
        if (k - k0 + 1 == g || k == M_ - 1) {
            reduce_half<<<2048, 256, 0, stream>>>(slots, g, k0, k - k0 + 1,
                                                  k0 == 0 ? 1 : 0, coefs, Gh);
            k0 = k + 1;
        }
    }
    convert_f16<<<512, 256, 0, stream>>>(f, fh);
    mfma_gemm<0><<<dim3(2, 128), 256, 0, stream>>>(Gh, fh, U1h, sum1);
    mfma_gemm<1><<<dim3(16, 128), 256, 0, stream>>>(Gh, U1h, (__half*)nullptr, sum2);
    fmean_kernel<<<1, 256, 0, stream>>>(f, out);
    finalize_kernel<<<64, 256, 0, stream>>>(sum1, sum2, out);
}

// Round 5
// 3356.275 us; speedup vs baseline: 6.1223x; 1.8376x over previous
//
#include <hip/hip_runtime.h>
#include <hip/hip_fp16.h>
#include <math.h>

// ---------------- constants ----------------
constexpr int   N_   = 2048;
constexpr int   DF_  = 256;
constexpr int   J_   = 8;
constexpr int   ELLW_= 64;
constexpr int   M_   = 256;          // coefficient array stride (256-pt DCT quadrature)
constexpr int   MUSE_= 128;          // Chebyshev terms actually used (degree 127)
constexpr float H_   = 1.01f;        // domain half-width  ([-0.01, 2.01])
constexpr float C0_  = 1.0f;         // domain center
constexpr float AF_  = 0.34657359027997264f;   // A = 3*ln(2)/6
constexpr float PI_F = 3.14159265358979323846f;

typedef _Float16 f16x8 __attribute__((ext_vector_type(8)));
typedef __attribute__((ext_vector_type(4))) float f32x4;
using u16 = unsigned short;

// ---------------- filter functions ----------------
__device__ __forceinline__ float g_hat_f(float x) {
    float val = 0.5f + 0.5f * cosf(2.f * PI_F * (x / AF_ + 0.5f));
    return (x <= 0.f && x > -AF_) ? val : 0.f;
}
__device__ __forceinline__ float wavelet_f(float lamb, int j) {
    float lmin = expf(AF_ * ((j - 1) / 3.0f - 1.0f));
    float lam  = fmaxf(lamb, lmin);
    return g_hat_f(logf(lam) - AF_ * (j - 1) / 3.0f);
}
__device__ __forceinline__ float filter_eval(float lamb, int jf) {
    if (jf == 0) {
        float g3 = 0.f;
        for (int j = 2; j <= 8; ++j) { float w = wavelet_f(lamb, j); g3 += w * w; }
        return sqrtf(fmaxf(1.5f - g3, 0.f));
    }
    return wavelet_f(lamb, jf + 1);
}

// ---------------- setup kernels ----------------
__global__ __launch_bounds__(256) void deg_kernel(const float* __restrict__ W,
                                                  float* __restrict__ dh,
                                                  float* __restrict__ dr) {
    int i = blockIdx.x, t = threadIdx.x;
    const float4* row = (const float4*)(W + (size_t)i * N_);
    float s = 0.f;
    for (int c = t; c < N_ / 4; c += 256) { float4 v = row[c]; s += v.x + v.y + v.z + v.w; }
    __shared__ float red[256];
    red[t] = s; __syncthreads();
    for (int o = 128; o; o >>= 1) { if (t < o) red[t] += red[t + o]; __syncthreads(); }
    if (t == 0) {
        float deg = red[0];
        float dhi = 1.f / sqrtf(fmaxf(deg, 1.f));
        dh[i] = dhi;
        dr[i] = (dhi * dhi * deg - C0_) / H_;
    }
}

// ELL build: all 64 entries pre-filled with (col=i, val=0) pads; cnt rounded up to mult of 8.
__global__ __launch_bounds__(64) void ell_kernel(const float* __restrict__ W,
                                                 const float* __restrict__ dh,
                                                 int* __restrict__ cnt,
                                                 int* __restrict__ cols,
                                                 float* __restrict__ vals) {
    int i = blockIdx.x, lane = threadIdx.x;
    cols[i * ELLW_ + lane] = i;            // pad defaults
    vals[i * ELLW_ + lane] = 0.f;
    __syncthreads();
    const float* row = W + (size_t)i * N_;
    unsigned long long lt = (1ull << lane) - 1ull;
    int base = 0;
    float dhi = dh[i];
    for (int c = 0; c < N_; c += 64) {
        float v = row[c + lane];
        unsigned long long m = __ballot(v != 0.f);
        if (v != 0.f) {
            int pos = base + __popcll(m & lt);
            if (pos < ELLW_) {
                cols[i * ELLW_ + pos] = c + lane;
                vals[i * ELLW_ + pos] = dhi * dh[c + lane] / H_;
            }
        }
        base += __popcll(m);
    }
    if (lane == 0) {
        int n = base < ELLW_ ? base : ELLW_;
        cnt[i] = (n + 7) & ~7;             // padded count (pads are no-ops)
    }
}

__global__ __launch_bounds__(256) void coef_kernel(float* __restrict__ coefs) {
    __shared__ float fv[J_][M_];
    int t = threadIdx.x;
    float theta = PI_F * (t + 0.5f) / M_;
    float lam = C0_ + H_ * cosf(theta);
    for (int j = 0; j < J_; ++j) fv[j][t] = filter_eval(lam, j);
    __syncthreads();
    for (int j = 0; j < J_; ++j) {
        float s = 0.f;
        for (int i = 0; i < M_; ++i)
            s += fv[j][i] * cosf(PI_F * t * (i + 0.5f) / M_);
        coefs[j * M_ + t] = s * ((t == 0 ? 1.f : 2.f) / M_);
    }
}

// slot0 = I (fp16), slot1 = scaled L-tilde (fp16)
__global__ __launch_bounds__(256) void init_slots(__half* __restrict__ S0, __half* __restrict__ S1,
                                                  const int* __restrict__ cnt, const int* __restrict__ cols,
                                                  const float* __restrict__ vals, const float* __restrict__ dr) {
    int i = blockIdx.x, t = threadIdx.x;
    size_t ro = (size_t)i * N_;
    for (int c = t * 8; c < N_; c += 2048) {
        *(uint4*)(S0 + ro + c) = uint4{0, 0, 0, 0};
        *(uint4*)(S1 + ro + c) = uint4{0, 0, 0, 0};
    }
    __syncthreads();
    int n = cnt[i];
    if (t < n) {
        int c = cols[i * ELLW_ + t];
        float v = -vals[i * ELLW_ + t];
        if (v != 0.f) S1[ro + c] = __float2half(v);   // skip pads (col=i, val=0)
    }
    __syncthreads();
    if (t == 0) {
        S0[ro + i] = __float2half(1.f);
        S1[ro + i] = __float2half(dr[i]);
    }
}

// ------- Chebyshev step, full fp16 state: S_k = 2*Ltilde*S_{k-1} - S_{k-2} ----------
// One block per row; 256 threads x 8 fp16 cols; edge loop unrolled by 8 (padded).
__global__ __launch_bounds__(256) void cheb_fp16(const __half* __restrict__ X,
                                                 const __half* __restrict__ Tprev,
                                                 __half* __restrict__ Tnext,
                                                 const int* __restrict__ cnt,
                                                 const int* __restrict__ cols,
                                                 const float* __restrict__ vals,
                                                 const float* __restrict__ dr) {
    int i   = blockIdx.x;
    int col = threadIdx.x * 8;
    __shared__ int   scols[ELLW_];
    __shared__ float svals[ELLW_];
    if (threadIdx.x < ELLW_) {
        scols[threadIdx.x] = cols[i * ELLW_ + threadIdx.x];
        svals[threadIdx.x] = vals[i * ELLW_ + threadIdx.x];
    }
    __syncthreads();
    int n = cnt[i];                          // multiple of 8 (or 0)
    float a[8] = {0, 0, 0, 0, 0, 0, 0, 0};
    for (int e0 = 0; e0 < n; e0 += 8) {
        uint4 q[8];
        float v[8];
#pragma unroll
        for (int u = 0; u < 8; ++u) {
            int c = scols[e0 + u];
            v[u] = svals[e0 + u];
            q[u] = *(const uint4*)(X + (size_t)c * N_ + col);
        }
#pragma unroll
        for (int u = 0; u < 8; ++u) {
            const __half2* h = (const __half2*)&q[u];
            float2 f0 = __half22float2(h[0]), f1 = __half22float2(h[1]);
            float2 f2 = __half22float2(h[2]), f3 = __half22float2(h[3]);
            a[0] -= v[u] * f0.x; a[1] -= v[u] * f0.y;
            a[2] -= v[u] * f1.x; a[3] -= v[u] * f1.y;
            a[4] -= v[u] * f2.x; a[5] -= v[u] * f2.y;
            a[6] -= v[u] * f3.x; a[7] -= v[u] * f3.y;
        }
    }
    size_t po = (size_t)i * N_ + col;
    {   // diagonal term
        float d = dr[i];
        uint4 q = *(const uint4*)(X + po);
        const __half2* h = (const __half2*)&q;
        float2 f0 = __half22float2(h[0]), f1 = __half22float2(h[1]);
        float2 f2 = __half22float2(h[2]), f3 = __half22float2(h[3]);
        a[0] += d * f0.x; a[1] += d * f0.y; a[2] += d * f1.x; a[3] += d * f1.y;
        a[4] += d * f2.x; a[5] += d * f2.y; a[6] += d * f3.x; a[7] += d * f3.y;
    }
    uint4 qp = *(const uint4*)(Tprev + po);
    const __half2* hp = (const __half2*)&qp;
    float2 p0 = __half22float2(hp[0]), p1 = __half22float2(hp[1]);
    float2 p2 = __half22float2(hp[2]), p3 = __half22float2(hp[3]);
    __half2 s0 = __floats2half2_rn(2.f * a[0] - p0.x, 2.f * a[1] - p0.y);
    __half2 s1 = __floats2half2_rn(2.f * a[2] - p1.x, 2.f * a[3] - p1.y);
    __half2 s2 = __floats2half2_rn(2.f * a[4] - p2.x, 2.f * a[5] - p2.y);
    __half2 s3 = __floats2half2_rn(2.f * a[6] - p3.x, 2.f * a[7] - p3.y);
    uint4 sq;
    sq.x = *(const unsigned int*)&s0; sq.y = *(const unsigned int*)&s1;
    sq.z = *(const unsigned int*)&s2; sq.w = *(const unsigned int*)&s3;
    *(uint4*)(Tnext + po) = sq;
}

// ---------------- group reduction: Gh_j += sum_{k in [k0,k0+nslot)} b_{jk} * slot(k%g) -------
__global__ __launch_bounds__(256) void reduce_half(const __half* __restrict__ slots,
                                                   int g, int k0, int nslot, int initG,
                                                   const float* __restrict__ coefs,
                                                   __half* __restrict__ Gh) {
    const size_t NSQ = (size_t)N_ * N_;
    size_t idx = ((size_t)blockIdx.x * 256 + threadIdx.x) * 8;
    __shared__ float sc[J_ * 64];
    for (int x = threadIdx.x; x < J_ * nslot; x += 256) {
        int j = x / nslot, s = x - j * nslot;
        sc[j * 64 + s] = coefs[j * M_ + k0 + s];
    }
    __syncthreads();
    float acc[J_][8];
#pragma unroll
    for (int j = 0; j < J_; ++j) {
        if (initG) {
#pragma unroll
            for (int r = 0; r < 8; ++r) acc[j][r] = 0.f;
        } else {
            uint4 q = *(const uint4*)(Gh + (size_t)j * NSQ + idx);
            const __half2* h = (const __half2*)&q;
            float2 f0 = __half22float2(h[0]), f1 = __half22float2(h[1]);
            float2 f2 = __half22float2(h[2]), f3 = __half22float2(h[3]);
            acc[j][0] = f0.x; acc[j][1] = f0.y; acc[j][2] = f1.x; acc[j][3] = f1.y;
            acc[j][4] = f2.x; acc[j][5] = f2.y; acc[j][6] = f3.x; acc[j][7] = f3.y;
        }
    }
    for (int s = 0; s < nslot; ++s) {
        int slot = (k0 + s) % g;
        uint4 q = *(const uint4*)(slots + (size_t)slot * NSQ + idx);
        const __half2* h = (const __half2*)&q;
        float2 f0 = __half22float2(h[0]), f1 = __half22float2(h[1]);
        float2 f2 = __half22float2(h[2]), f3 = __half22float2(h[3]);
        float f[8] = {f0.x, f0.y, f1.x, f1.y, f2.x, f2.y, f3.x, f3.y};
#pragma unroll
        for (int j = 0; j < J_; ++j) {
            float c = sc[j * 64 + s];
#pragma unroll
            for (int r = 0; r < 8; ++r) acc[j][r] += c * f[r];
        }
    }
#pragma unroll
    for (int j = 0; j < J_; ++j) {
        __half2 o0 = __floats2half2_rn(acc[j][0], acc[j][1]);
        __half2 o1 = __floats2half2_rn(acc[j][2], acc[j][3]);
        __half2 o2 = __floats2half2_rn(acc[j][4], acc[j][5]);
        __half2 o3 = __floats2half2_rn(acc[j][6], acc[j][7]);
        uint4 o;
        o.x = *(const unsigned int*)&o0; o.y = *(const unsigned int*)&o1;
        o.z = *(const unsigned int*)&o2; o.w = *(const unsigned int*)&o3;
        *(uint4*)(Gh + (size_t)j * NSQ + idx) = o;
    }
}

// ---------------- f32 -> f16 convert ----------------
__global__ __launch_bounds__(256) void convert_f16(const float* __restrict__ src,
                                                   __half* __restrict__ dst) {
    size_t i4 = ((size_t)blockIdx.x * 256 + threadIdx.x) * 4;
    float4 v = *(const float4*)(src + i4);
    __half2 h0 = __floats2half2_rn(v.x, v.y);
    __half2 h1 = __floats2half2_rn(v.z, v.w);
    uint2 o;
    o.x = *(const unsigned int*)&h0; o.y = *(const unsigned int*)&h1;
    *(uint2*)(dst + i4) = o;
}

// ---------------- MFMA fp16 GEMM with fused |.| + column-sum epilogue ----------------
// C = Gh[16384 x 2048] * B.  MODE 0: B = fh (2048 x 256), store U1h fp16 [i][j*256+d],
// colsum1[j*256+d].  MODE 1: B = U1h (2048 x 2048), colsum2[(b*8+j)*256+d].
template <int MODE>
__global__ __launch_bounds__(256) void mfma_gemm(const __half* __restrict__ A,
                                                 const __half* __restrict__ B,
                                                 __half* __restrict__ Uout,
                                                 float* __restrict__ colsum) {
    constexpr int LDK = 72;
    constexpr int NB  = (MODE == 0) ? 256 : 2048;
    __shared__ u16 As[128 * LDK];
    __shared__ u16 Bs[128 * LDK];
    int tid = threadIdx.x;
    int w = tid >> 6, lane = tid & 63;
    int wr = w >> 1, wc = w & 1;
    int gm0 = blockIdx.y * 128, n0 = blockIdx.x * 128;
    f32x4 acc[4][4];
#pragma unroll
    for (int mf = 0; mf < 4; ++mf)
#pragma unroll
        for (int nf = 0; nf < 4; ++nf) acc[mf][nf] = (f32x4){0.f, 0.f, 0.f, 0.f};

    int r = tid >> 1, h = tid & 1;
    int kk = tid >> 2, seg = tid & 3;
    for (int k0 = 0; k0 < 2048; k0 += 64) {
        const u16* ap = (const u16*)A + (size_t)(gm0 + r) * 2048 + k0 + h * 32;
        u16* as = As + r * LDK + h * 32;
        *(uint4*)(as + 0)  = *(const uint4*)(ap + 0);
        *(uint4*)(as + 8)  = *(const uint4*)(ap + 8);
        *(uint4*)(as + 16) = *(const uint4*)(ap + 16);
        *(uint4*)(as + 24) = *(const uint4*)(ap + 24);
        const u16* bp = (const u16*)B + (size_t)(k0 + kk) * NB + n0 + seg * 32;
        uint4 q0 = *(const uint4*)(bp + 0);
        uint4 q1 = *(const uint4*)(bp + 8);
        uint4 q2 = *(const uint4*)(bp + 16);
        uint4 q3 = *(const uint4*)(bp + 24);
        u16* bs = Bs + (seg * 32) * LDK + kk;
#define WR8(Q, base) \
        bs[(base + 0) * LDK] = (u16)(Q.x);       bs[(base + 1) * LDK] = (u16)(Q.x >> 16); \
        bs[(base + 2) * LDK] = (u16)(Q.y);       bs[(base + 3) * LDK] = (u16)(Q.y >> 16); \
        bs[(base + 4) * LDK] = (u16)(Q.z);       bs[(base + 5) * LDK] = (u16)(Q.z >> 16); \
        bs[(base + 6) * LDK] = (u16)(Q.w);       bs[(base + 7) * LDK] = (u16)(Q.w >> 16);
        WR8(q0, 0) WR8(q1, 8) WR8(q2, 16) WR8(q3, 24)
#undef WR8
        __syncthreads();
#pragma unroll
        for (int s = 0; s < 2; ++s) {
            int krd = s * 32 + (lane >> 4) * 8;
            f16x8 af[4], bfv[4];
#pragma unroll
            for (int mf = 0; mf < 4; ++mf)
                af[mf] = *(const f16x8*)(As + (wr * 64 + mf * 16 + (lane & 15)) * LDK + krd);
#pragma unroll
            for (int nf = 0; nf < 4; ++nf)
                bfv[nf] = *(const f16x8*)(Bs + (wc * 64 + nf * 16 + (lane & 15)) * LDK + krd);
#pragma unroll
            for (int mf = 0; mf < 4; ++mf)
#pragma unroll
                for (int nf = 0; nf < 4; ++nf)
                    acc[mf][nf] = __builtin_amdgcn_mfma_f32_16x16x32_f16(
                        af[mf], bfv[nf], acc[mf][nf], 0, 0, 0);
        }
        __syncthreads();
    }
    int j = gm0 >> 11;
#pragma unroll
    for (int nf = 0; nf < 4; ++nf) {
        float cs = 0.f;
#pragma unroll
        for (int mf = 0; mf < 4; ++mf) {
#pragma unroll
            for (int rr = 0; rr < 4; ++rr) {
                float val = fabsf(acc[mf][nf][rr]);
                cs += val;
                if (MODE == 0) {
                    int gm = gm0 + wr * 64 + mf * 16 + (lane >> 4) * 4 + rr;
                    int i = gm & (N_ - 1);
                    int d = n0 + wc * 64 + nf * 16 + (lane & 15);
                    Uout[(size_t)i * 2048 + j * 256 + d] = __float2half(val);
                }
            }
        }
        cs += __shfl_xor(cs, 16);
        cs += __shfl_xor(cs, 32);
        if ((lane >> 4) == 0) {
            int colg = n0 + wc * 64 + nf * 16 + lane;
            if (MODE == 0) atomicAdd(&colsum[j * 256 + colg], cs);
            else atomicAdd(&colsum[(((colg >> 8) * 8 + j) << 8) + (colg & 255)], cs);
        }
    }
}

__global__ __launch_bounds__(256) void fmean_kernel(const float* __restrict__ f, float* __restrict__ out) {
    int d = threadIdx.x;
    float s = 0.f;
    for (int n = 0; n < N_; ++n) s += f[(size_t)n * DF_ + d];
    out[d] = s * (1.f / N_);
}

__global__ __launch_bounds__(256) void finalize_kernel(const float* __restrict__ sum1,
                                                       const float* __restrict__ sum2,
                                                       float* __restrict__ out) {
    int idx = blockIdx.x * 256 + threadIdx.x;
    if (idx < 2048)  out[256 + idx]  = sum1[idx] * (1.f / N_);
    if (idx < 16384) out[2304 + idx] = sum2[idx] * (1.f / N_);
}

// ---------------- host orchestration ----------------
extern "C" void kernel_launch(void* const* d_in, const int* in_sizes, int n_in,
                              void* d_out, int out_size, void* d_ws, size_t ws_size,
                              hipStream_t stream) {
    (void)in_sizes; (void)n_in;
    const float* W = (const float*)d_in[0];
    const float* f = (const float*)d_in[1];
    float* out = (float*)d_out;
    char* base = (char*)d_ws;
    size_t off = 0;
    auto take = [&](size_t bytes) -> char* {
        off = (off + 255) & ~(size_t)255;
        char* p = base + off; off += bytes; return p;
    };
    const size_t NSQ = (size_t)N_ * N_;
    float*  dh    = (float*)take((size_t)N_ * 4);
    float*  dr    = (float*)take((size_t)N_ * 4);
    int*    cnt   = (int*)take((size_t)N_ * 4);
    int*    cols  = (int*)take((size_t)N_ * ELLW_ * 4);
    float*  vals  = (float*)take((size_t)N_ * ELLW_ * 4);
    float*  coefs = (float*)take((size_t)J_ * M_ * 4);
    float*  sum1  = (float*)take(2048 * 4);
    float*  sum2  = (float*)take(16384 * 4);
    __half* Gh    = (__half*)take(NSQ * 2 * J_);                 //  67.1 MB
    __half* U1h   = (__half*)take((size_t)N_ * 2048 * 2);        //   8.4 MB
    __half* fh    = (__half*)take((size_t)N_ * DF_ * 2);         //   1.0 MB
    off = (off + 255) & ~(size_t)255;
    const size_t slotBytes = NSQ * 2;
    long long rem = (long long)ws_size - (long long)off;
    int g = (int)(rem / (long long)slotBytes);
    if (g > 24) g = 24;
    if (g < 3) {                       // workspace too small — cannot run
        hipMemsetAsync(d_out, 0, (size_t)out_size * 4, stream);
        return;
    }
    __half* slots = (__half*)take((size_t)g * slotBytes);

    deg_kernel<<<N_, 256, 0, stream>>>(W, dh, dr);
    ell_kernel<<<N_, 64, 0, stream>>>(W, dh, cnt, cols, vals);
    coef_kernel<<<1, 256, 0, stream>>>(coefs);
    hipMemsetAsync(sum1, 0, 2048 * 4, stream);
    hipMemsetAsync(sum2, 0, 16384 * 4, stream);
    init_slots<<<N_, 256, 0, stream>>>(slots, slots + NSQ, cnt, cols, vals, dr);

    int k0 = 0;                        // start of current un-reduced group
    for (int k = 2; k < MUSE_; ++k) {
        cheb_fp16<<<N_, 256, 0, stream>>>(
            slots + (size_t)((k - 1) % g) * NSQ,
            slots + (size_t)((k - 2) % g) * NSQ,
            slots + (size_t)(k % g) * NSQ,
            cnt, cols, vals, dr);
        if (k - k0 + 1 == g || k == MUSE_ - 1) {
            reduce_half<<<2048, 256, 0, stream>>>(slots, g, k0, k - k0 + 1,
                                                  k0 == 0 ? 1 : 0, coefs, Gh);
            k0 = k + 1;
        }
    }
    convert_f16<<<512, 256, 0, stream>>>(f, fh);
    mfma_gemm<0><<<dim3(2, 128), 256, 0, stream>>>(Gh, fh, U1h, sum1);
    mfma_gemm<1><<<dim3(16, 128), 256, 0, stream>>>(Gh, U1h, (__half*)nullptr, sum2);
    fmean_kernel<<<1, 256, 0, stream>>>(f, out);
    finalize_kernel<<<64, 256, 0, stream>>>(sum1, sum2, out);
}

// Round 6
// 2342.626 us; speedup vs baseline: 8.7714x; 1.4327x over previous
//
#include <hip/hip_runtime.h>
#include <hip/hip_fp16.h>
#include <math.h>

// ---------------- constants ----------------
constexpr int   N_   = 2048;
constexpr int   DF_  = 256;
constexpr int   J_   = 8;
constexpr int   ELLW_= 64;
constexpr int   M_   = 256;          // coefficient array stride (256-pt DCT quadrature)
constexpr int   MUSE_= 128;          // Chebyshev terms actually used (degree 127)
constexpr float H_   = 1.01f;        // domain half-width  ([-0.01, 2.01])
constexpr float C0_  = 1.0f;         // domain center
constexpr float AF_  = 0.34657359027997264f;   // A = 3*ln(2)/6
constexpr float PI_F = 3.14159265358979323846f;

typedef _Float16 f16x8 __attribute__((ext_vector_type(8)));
typedef __attribute__((ext_vector_type(4))) float f32x4;
using u16 = unsigned short;

// ---------------- filter functions ----------------
__device__ __forceinline__ float g_hat_f(float x) {
    float val = 0.5f + 0.5f * cosf(2.f * PI_F * (x / AF_ + 0.5f));
    return (x <= 0.f && x > -AF_) ? val : 0.f;
}
__device__ __forceinline__ float wavelet_f(float lamb, int j) {
    float lmin = expf(AF_ * ((j - 1) / 3.0f - 1.0f));
    float lam  = fmaxf(lamb, lmin);
    return g_hat_f(logf(lam) - AF_ * (j - 1) / 3.0f);
}
__device__ __forceinline__ float filter_eval(float lamb, int jf) {
    if (jf == 0) {
        float g3 = 0.f;
        for (int j = 2; j <= 8; ++j) { float w = wavelet_f(lamb, j); g3 += w * w; }
        return sqrtf(fmaxf(1.5f - g3, 0.f));
    }
    return wavelet_f(lamb, jf + 1);
}

// ---------------- setup kernels ----------------
__global__ __launch_bounds__(256) void deg_kernel(const float* __restrict__ W,
                                                  float* __restrict__ dh,
                                                  float* __restrict__ dr) {
    int i = blockIdx.x, t = threadIdx.x;
    const float4* row = (const float4*)(W + (size_t)i * N_);
    float s = 0.f;
    for (int c = t; c < N_ / 4; c += 256) { float4 v = row[c]; s += v.x + v.y + v.z + v.w; }
    __shared__ float red[256];
    red[t] = s; __syncthreads();
    for (int o = 128; o; o >>= 1) { if (t < o) red[t] += red[t + o]; __syncthreads(); }
    if (t == 0) {
        float deg = red[0];
        float dhi = 1.f / sqrtf(fmaxf(deg, 1.f));
        dh[i] = dhi;
        dr[i] = (dhi * dhi * deg - C0_) / H_;
    }
}

// ELL build: all 64 entries pre-filled with (col=i, val=0) pads; cnt rounded up to mult of 8.
__global__ __launch_bounds__(64) void ell_kernel(const float* __restrict__ W,
                                                 const float* __restrict__ dh,
                                                 int* __restrict__ cnt,
                                                 int* __restrict__ cols,
                                                 float* __restrict__ vals) {
    int i = blockIdx.x, lane = threadIdx.x;
    cols[i * ELLW_ + lane] = i;            // pad defaults
    vals[i * ELLW_ + lane] = 0.f;
    __syncthreads();
    const float* row = W + (size_t)i * N_;
    unsigned long long lt = (1ull << lane) - 1ull;
    int base = 0;
    float dhi = dh[i];
    for (int c = 0; c < N_; c += 64) {
        float v = row[c + lane];
        unsigned long long m = __ballot(v != 0.f);
        if (v != 0.f) {
            int pos = base + __popcll(m & lt);
            if (pos < ELLW_) {
                cols[i * ELLW_ + pos] = c + lane;
                vals[i * ELLW_ + pos] = dhi * dh[c + lane] / H_;
            }
        }
        base += __popcll(m);
    }
    if (lane == 0) {
        int n = base < ELLW_ ? base : ELLW_;
        cnt[i] = (n + 7) & ~7;             // padded count (pads are no-ops)
    }
}

__global__ __launch_bounds__(256) void coef_kernel(float* __restrict__ coefs) {
    __shared__ float fv[J_][M_];
    int t = threadIdx.x;
    float theta = PI_F * (t + 0.5f) / M_;
    float lam = C0_ + H_ * cosf(theta);
    for (int j = 0; j < J_; ++j) fv[j][t] = filter_eval(lam, j);
    __syncthreads();
    for (int j = 0; j < J_; ++j) {
        float s = 0.f;
        for (int i = 0; i < M_; ++i)
            s += fv[j][i] * cosf(PI_F * t * (i + 0.5f) / M_);
        coefs[j * M_ + t] = s * ((t == 0 ? 1.f : 2.f) / M_);
    }
}

// slot0 = I (fp16), slot1 = scaled L-tilde (fp16)
__global__ __launch_bounds__(256) void init_slots(__half* __restrict__ S0, __half* __restrict__ S1,
                                                  const int* __restrict__ cnt, const int* __restrict__ cols,
                                                  const float* __restrict__ vals, const float* __restrict__ dr) {
    int i = blockIdx.x, t = threadIdx.x;
    size_t ro = (size_t)i * N_;
    for (int c = t * 8; c < N_; c += 2048) {
        *(uint4*)(S0 + ro + c) = uint4{0, 0, 0, 0};
        *(uint4*)(S1 + ro + c) = uint4{0, 0, 0, 0};
    }
    __syncthreads();
    int n = cnt[i];
    if (t < n) {
        int c = cols[i * ELLW_ + t];
        float v = -vals[i * ELLW_ + t];
        if (v != 0.f) S1[ro + c] = __float2half(v);   // skip pads (col=i, val=0)
    }
    __syncthreads();
    if (t == 0) {
        S0[ro + i] = __float2half(1.f);
        S1[ro + i] = __float2half(dr[i]);
    }
}

// ------- Chebyshev step, XCD-striped: S_k = 2*Ltilde*S_{k-1} - S_{k-2} ----------
// blockIdx.x & 7 = column stripe (256 cols, 512B fp16) -> one XCD via round-robin
// dispatch; stripe of the iterate (1 MB) stays L2-resident across ALL steps since
// the stripe->XCD map is fixed. 8 rows/block, 32 lanes/row, 16B loads per edge.
__global__ __launch_bounds__(256) void cheb_fp16(const __half* __restrict__ X,
                                                 const __half* __restrict__ Tprev,
                                                 __half* __restrict__ Tnext,
                                                 const int* __restrict__ cnt,
                                                 const int* __restrict__ cols,
                                                 const float* __restrict__ vals,
                                                 const float* __restrict__ dr) {
    int strp = blockIdx.x & 7;
    int rg   = blockIdx.x >> 3;
    int tr   = threadIdx.x >> 5;           // 0..7: row within block
    int lr   = threadIdx.x & 31;
    int i    = rg * 8 + tr;
    int col  = strp * 256 + lr * 8;
    __shared__ int   scols[8][ELLW_];
    __shared__ float svals[8][ELLW_];
    {
        int e = threadIdx.x & 63, r0 = threadIdx.x >> 6;      // r0 in 0..3
        int gi0 = (rg * 8 + r0) * ELLW_ + e;
        int gi1 = (rg * 8 + r0 + 4) * ELLW_ + e;
        scols[r0][e] = cols[gi0];     svals[r0][e] = vals[gi0];
        scols[r0 + 4][e] = cols[gi1]; svals[r0 + 4][e] = vals[gi1];
    }
    __syncthreads();
    int n = cnt[i];                          // multiple of 8 (or 0)
    float a[8] = {0, 0, 0, 0, 0, 0, 0, 0};
    for (int e0 = 0; e0 < n; e0 += 8) {
        uint4 q[8];
        float v[8];
#pragma unroll
        for (int u = 0; u < 8; ++u) {
            int c = scols[tr][e0 + u];
            v[u] = svals[tr][e0 + u];
            q[u] = *(const uint4*)(X + (size_t)c * N_ + col);
        }
#pragma unroll
        for (int u = 0; u < 8; ++u) {
            const __half2* h = (const __half2*)&q[u];
            float2 f0 = __half22float2(h[0]), f1 = __half22float2(h[1]);
            float2 f2 = __half22float2(h[2]), f3 = __half22float2(h[3]);
            a[0] -= v[u] * f0.x; a[1] -= v[u] * f0.y;
            a[2] -= v[u] * f1.x; a[3] -= v[u] * f1.y;
            a[4] -= v[u] * f2.x; a[5] -= v[u] * f2.y;
            a[6] -= v[u] * f3.x; a[7] -= v[u] * f3.y;
        }
    }
    size_t po = (size_t)i * N_ + col;
    {   // diagonal term
        float d = dr[i];
        uint4 q = *(const uint4*)(X + po);
        const __half2* h = (const __half2*)&q;
        float2 f0 = __half22float2(h[0]), f1 = __half22float2(h[1]);
        float2 f2 = __half22float2(h[2]), f3 = __half22float2(h[3]);
        a[0] += d * f0.x; a[1] += d * f0.y; a[2] += d * f1.x; a[3] += d * f1.y;
        a[4] += d * f2.x; a[5] += d * f2.y; a[6] += d * f3.x; a[7] += d * f3.y;
    }
    uint4 qp = *(const uint4*)(Tprev + po);
    const __half2* hp = (const __half2*)&qp;
    float2 p0 = __half22float2(hp[0]), p1 = __half22float2(hp[1]);
    float2 p2 = __half22float2(hp[2]), p3 = __half22float2(hp[3]);
    __half2 s0 = __floats2half2_rn(2.f * a[0] - p0.x, 2.f * a[1] - p0.y);
    __half2 s1 = __floats2half2_rn(2.f * a[2] - p1.x, 2.f * a[3] - p1.y);
    __half2 s2 = __floats2half2_rn(2.f * a[4] - p2.x, 2.f * a[5] - p2.y);
    __half2 s3 = __floats2half2_rn(2.f * a[6] - p3.x, 2.f * a[7] - p3.y);
    uint4 sq;
    sq.x = *(const unsigned int*)&s0; sq.y = *(const unsigned int*)&s1;
    sq.z = *(const unsigned int*)&s2; sq.w = *(const unsigned int*)&s3;
    *(uint4*)(Tnext + po) = sq;
}

// ---------------- group reduction: Gh_j += sum_{k in [k0,k0+nslot)} b_{jk} * slot(k%g) -------
__global__ __launch_bounds__(256) void reduce_half(const __half* __restrict__ slots,
                                                   int g, int k0, int nslot, int initG,
                                                   const float* __restrict__ coefs,
                                                   __half* __restrict__ Gh) {
    const size_t NSQ = (size_t)N_ * N_;
    size_t idx = ((size_t)blockIdx.x * 256 + threadIdx.x) * 8;
    __shared__ float sc[J_ * 64];
    for (int x = threadIdx.x; x < J_ * nslot; x += 256) {
        int j = x / nslot, s = x - j * nslot;
        sc[j * 64 + s] = coefs[j * M_ + k0 + s];
    }
    __syncthreads();
    float acc[J_][8];
#pragma unroll
    for (int j = 0; j < J_; ++j) {
        if (initG) {
#pragma unroll
            for (int r = 0; r < 8; ++r) acc[j][r] = 0.f;
        } else {
            uint4 q = *(const uint4*)(Gh + (size_t)j * NSQ + idx);
            const __half2* h = (const __half2*)&q;
            float2 f0 = __half22float2(h[0]), f1 = __half22float2(h[1]);
            float2 f2 = __half22float2(h[2]), f3 = __half22float2(h[3]);
            acc[j][0] = f0.x; acc[j][1] = f0.y; acc[j][2] = f1.x; acc[j][3] = f1.y;
            acc[j][4] = f2.x; acc[j][5] = f2.y; acc[j][6] = f3.x; acc[j][7] = f3.y;
        }
    }
    for (int s = 0; s < nslot; ++s) {
        int slot = (k0 + s) % g;
        uint4 q = *(const uint4*)(slots + (size_t)slot * NSQ + idx);
        const __half2* h = (const __half2*)&q;
        float2 f0 = __half22float2(h[0]), f1 = __half22float2(h[1]);
        float2 f2 = __half22float2(h[2]), f3 = __half22float2(h[3]);
        float f[8] = {f0.x, f0.y, f1.x, f1.y, f2.x, f2.y, f3.x, f3.y};
#pragma unroll
        for (int j = 0; j < J_; ++j) {
            float c = sc[j * 64 + s];
#pragma unroll
            for (int r = 0; r < 8; ++r) acc[j][r] += c * f[r];
        }
    }
#pragma unroll
    for (int j = 0; j < J_; ++j) {
        __half2 o0 = __floats2half2_rn(acc[j][0], acc[j][1]);
        __half2 o1 = __floats2half2_rn(acc[j][2], acc[j][3]);
        __half2 o2 = __floats2half2_rn(acc[j][4], acc[j][5]);
        __half2 o3 = __floats2half2_rn(acc[j][6], acc[j][7]);
        uint4 o;
        o.x = *(const unsigned int*)&o0; o.y = *(const unsigned int*)&o1;
        o.z = *(const unsigned int*)&o2; o.w = *(const unsigned int*)&o3;
        *(uint4*)(Gh + (size_t)j * NSQ + idx) = o;
    }
}

// ---------------- f [2048][256] f32  ->  fhT [256][2048] f16 (transposed) ----------------
__global__ __launch_bounds__(256) void transpose_f16(const float* __restrict__ src,
                                                     __half* __restrict__ dst) {
    int d = blockIdx.x;                    // 256 output rows
    int i0 = threadIdx.x * 8;              // 8 nodes per thread
    __half h[8];
#pragma unroll
    for (int u = 0; u < 8; ++u) h[u] = __float2half(src[(size_t)(i0 + u) * DF_ + d]);
    uint4 o;
    __half2* hp = (__half2*)&o;
    hp[0] = __half2{h[0], h[1]}; hp[1] = __half2{h[2], h[3]};
    hp[2] = __half2{h[4], h[5]}; hp[3] = __half2{h[6], h[7]};
    *(uint4*)(dst + (size_t)d * N_ + i0) = o;
}

// ---------------- MFMA fp16 GEMM, both operands k-major, XOR-swizzled LDS --------------
// C = Gh[16384 x 2048] * BT^T.  BT rows are k-major length 2048.
// MODE 0: BT = fhT [256][2048]; writes U1T [2048 cols][2048 nodes] + colsum1[j*256+d].
// MODE 1: BT = U1T [2048][2048]; colsum2[(b*8+j)*256+d].
template <int MODE>
__global__ __launch_bounds__(256) void mfma_gemm(const __half* __restrict__ A,
                                                 const __half* __restrict__ BT,
                                                 __half* __restrict__ U1T,
                                                 float* __restrict__ colsum) {
    __shared__ u16 As[128 * 64];
    __shared__ u16 Bs[128 * 64];
    int tid = threadIdx.x;
    int w = tid >> 6, lane = tid & 63;
    int wr = w >> 1, wc = w & 1;
    int gm0 = blockIdx.y * 128, n0 = blockIdx.x * 128;
    f32x4 acc[4][4];
#pragma unroll
    for (int mf = 0; mf < 4; ++mf)
#pragma unroll
        for (int nf = 0; nf < 4; ++nf) acc[mf][nf] = (f32x4){0.f, 0.f, 0.f, 0.f};

    int r = tid >> 1, h = tid & 1;         // 128 rows, 2 threads/row (32 u16 each)
    int sw = r & 7;
    for (int k0 = 0; k0 < 2048; k0 += 64) {
        const u16* ap = (const u16*)A + (size_t)(gm0 + r) * 2048 + k0 + h * 32;
        const u16* bp = (const u16*)BT + (size_t)(n0 + r) * 2048 + k0 + h * 32;
#pragma unroll
        for (int q = 0; q < 4; ++q) {
            int blk = (h * 4 + q) ^ sw;    // XOR swizzle in 8-u16 (16B) granules
            *(uint4*)(As + r * 64 + blk * 8) = *(const uint4*)(ap + q * 8);
            *(uint4*)(Bs + r * 64 + blk * 8) = *(const uint4*)(bp + q * 8);
        }
        __syncthreads();
#pragma unroll
        for (int s = 0; s < 2; ++s) {
            f16x8 af[4], bfv[4];
#pragma unroll
            for (int mf = 0; mf < 4; ++mf) {
                int row = wr * 64 + mf * 16 + (lane & 15);
                int blk = (s * 4 + (lane >> 4)) ^ (row & 7);
                af[mf] = *(const f16x8*)(As + row * 64 + blk * 8);
            }
#pragma unroll
            for (int nf = 0; nf < 4; ++nf) {
                int row = wc * 64 + nf * 16 + (lane & 15);
                int blk = (s * 4 + (lane >> 4)) ^ (row & 7);
                bfv[nf] = *(const f16x8*)(Bs + row * 64 + blk * 8);
            }
#pragma unroll
            for (int mf = 0; mf < 4; ++mf)
#pragma unroll
                for (int nf = 0; nf < 4; ++nf)
                    acc[mf][nf] = __builtin_amdgcn_mfma_f32_16x16x32_f16(
                        af[mf], bfv[nf], acc[mf][nf], 0, 0, 0);
        }
        __syncthreads();
    }
    // epilogue: C frag layout col = lane&15, row = (lane>>4)*4 + reg
    int j = gm0 >> 11;
    int ibase = (gm0 & (N_ - 1)) + wr * 64 + (lane >> 4) * 4;
#pragma unroll
    for (int nf = 0; nf < 4; ++nf) {
        int d = n0 + wc * 64 + nf * 16 + (lane & 15);
        float cs = 0.f;
#pragma unroll
        for (int mf = 0; mf < 4; ++mf) {
            float v0 = fabsf(acc[mf][nf][0]);
            float v1 = fabsf(acc[mf][nf][1]);
            float v2 = fabsf(acc[mf][nf][2]);
            float v3 = fabsf(acc[mf][nf][3]);
            cs += v0 + v1 + v2 + v3;
            if (MODE == 0) {
                ushort4 o;
                o.x = __half_as_ushort(__float2half(v0));
                o.y = __half_as_ushort(__float2half(v1));
                o.z = __half_as_ushort(__float2half(v2));
                o.w = __half_as_ushort(__float2half(v3));
                // U1T[(j*256+d)][node] ; 4 consecutive nodes = 8B store
                *(ushort4*)(U1T + (size_t)(j * 256 + d) * N_ + ibase + mf * 16) = o;
            }
        }
        cs += __shfl_xor(cs, 16);
        cs += __shfl_xor(cs, 32);
        if ((lane >> 4) == 0) {
            int colg = n0 + wc * 64 + nf * 16 + lane;
            if (MODE == 0) atomicAdd(&colsum[j * 256 + colg], cs);
            else atomicAdd(&colsum[(((colg >> 8) * 8 + j) << 8) + (colg & 255)], cs);
        }
    }
}

__global__ __launch_bounds__(256) void fmean_kernel(const float* __restrict__ f, float* __restrict__ out) {
    int d = threadIdx.x;
    float s = 0.f;
    for (int n = 0; n < N_; ++n) s += f[(size_t)n * DF_ + d];
    out[d] = s * (1.f / N_);
}

__global__ __launch_bounds__(256) void finalize_kernel(const float* __restrict__ sum1,
                                                       const float* __restrict__ sum2,
                                                       float* __restrict__ out) {
    int idx = blockIdx.x * 256 + threadIdx.x;
    if (idx < 2048)  out[256 + idx]  = sum1[idx] * (1.f / N_);
    if (idx < 16384) out[2304 + idx] = sum2[idx] * (1.f / N_);
}

// ---------------- host orchestration ----------------
extern "C" void kernel_launch(void* const* d_in, const int* in_sizes, int n_in,
                              void* d_out, int out_size, void* d_ws, size_t ws_size,
                              hipStream_t stream) {
    (void)in_sizes; (void)n_in;
    const float* W = (const float*)d_in[0];
    const float* f = (const float*)d_in[1];
    float* out = (float*)d_out;
    char* base = (char*)d_ws;
    size_t off = 0;
    auto take = [&](size_t bytes) -> char* {
        off = (off + 255) & ~(size_t)255;
        char* p = base + off; off += bytes; return p;
    };
    const size_t NSQ = (size_t)N_ * N_;
    float*  dh    = (float*)take((size_t)N_ * 4);
    float*  dr    = (float*)take((size_t)N_ * 4);
    int*    cnt   = (int*)take((size_t)N_ * 4);
    int*    cols  = (int*)take((size_t)N_ * ELLW_ * 4);
    float*  vals  = (float*)take((size_t)N_ * ELLW_ * 4);
    float*  coefs = (float*)take((size_t)J_ * M_ * 4);
    float*  sum1  = (float*)take(2048 * 4);
    float*  sum2  = (float*)take(16384 * 4);
    __half* Gh    = (__half*)take(NSQ * 2 * J_);                 //  67.1 MB
    __half* U1T   = (__half*)take((size_t)N_ * 2048 * 2);        //   8.4 MB
    __half* fhT   = (__half*)take((size_t)N_ * DF_ * 2);         //   1.0 MB
    off = (off + 255) & ~(size_t)255;
    const size_t slotBytes = NSQ * 2;
    long long rem = (long long)ws_size - (long long)off;
    int g = (int)(rem / (long long)slotBytes);
    if (g > 24) g = 24;
    if (g < 3) {                       // workspace too small — cannot run
        hipMemsetAsync(d_out, 0, (size_t)out_size * 4, stream);
        return;
    }
    __half* slots = (__half*)take((size_t)g * slotBytes);

    deg_kernel<<<N_, 256, 0, stream>>>(W, dh, dr);
    ell_kernel<<<N_, 64, 0, stream>>>(W, dh, cnt, cols, vals);
    coef_kernel<<<1, 256, 0, stream>>>(coefs);
    hipMemsetAsync(sum1, 0, 2048 * 4, stream);
    hipMemsetAsync(sum2, 0, 16384 * 4, stream);
    init_slots<<<N_, 256, 0, stream>>>(slots, slots + NSQ, cnt, cols, vals, dr);

    int k0 = 0;                        // start of current un-reduced group
    for (int k = 2; k < MUSE_; ++k) {
        cheb_fp16<<<2048, 256, 0, stream>>>(
            slots + (size_t)((k - 1) % g) * NSQ,
            slots + (size_t)((k - 2) % g) * NSQ,
            slots + (size_t)(k % g) * NSQ,
            cnt, cols, vals, dr);
        if (k - k0 + 1 == g || k == MUSE_ - 1) {
            reduce_half<<<2048, 256, 0, stream>>>(slots, g, k0, k - k0 + 1,
                                                  k0 == 0 ? 1 : 0, coefs, Gh);
            k0 = k + 1;
        }
    }
    transpose_f16<<<DF_, 256, 0, stream>>>(f, fhT);
    mfma_gemm<0><<<dim3(2, 128), 256, 0, stream>>>(Gh, fhT, U1T, sum1);
    mfma_gemm<1><<<dim3(16, 128), 256, 0, stream>>>(Gh, U1T, (__half*)nullptr, sum2);
    fmean_kernel<<<1, 256, 0, stream>>>(f, out);
    finalize_kernel<<<64, 256, 0, stream>>>(sum1, sum2, out);
}

// Round 7
// 2129.899 us; speedup vs baseline: 9.6474x; 1.0999x over previous
//
#include <hip/hip_runtime.h>
#include <hip/hip_fp16.h>
#include <math.h>

// ---------------- constants ----------------
constexpr int   N_   = 2048;
constexpr int   DF_  = 256;
constexpr int   J_   = 8;
constexpr int   ELLW_= 64;
constexpr int   M_   = 256;          // coefficient array stride (256-pt DCT quadrature)
constexpr int   MUSE_= 96;           // Chebyshev terms actually used (degree 95)
constexpr int   GCAP_= 20;           // slot ring size cap (slots+Gh fit 256MB L3)
constexpr float H_   = 1.01f;        // domain half-width  ([-0.01, 2.01])
constexpr float C0_  = 1.0f;         // domain center
constexpr float AF_  = 0.34657359027997264f;   // A = 3*ln(2)/6
constexpr float PI_F = 3.14159265358979323846f;

typedef _Float16 f16x8 __attribute__((ext_vector_type(8)));
typedef __attribute__((ext_vector_type(4))) float f32x4;
using u16 = unsigned short;

// ---------------- filter functions ----------------
__device__ __forceinline__ float g_hat_f(float x) {
    float val = 0.5f + 0.5f * cosf(2.f * PI_F * (x / AF_ + 0.5f));
    return (x <= 0.f && x > -AF_) ? val : 0.f;
}
__device__ __forceinline__ float wavelet_f(float lamb, int j) {
    float lmin = expf(AF_ * ((j - 1) / 3.0f - 1.0f));
    float lam  = fmaxf(lamb, lmin);
    return g_hat_f(logf(lam) - AF_ * (j - 1) / 3.0f);
}
__device__ __forceinline__ float filter_eval(float lamb, int jf) {
    if (jf == 0) {
        float g3 = 0.f;
        for (int j = 2; j <= 8; ++j) { float w = wavelet_f(lamb, j); g3 += w * w; }
        return sqrtf(fmaxf(1.5f - g3, 0.f));
    }
    return wavelet_f(lamb, jf + 1);
}

// ---------------- setup kernels ----------------
__global__ __launch_bounds__(256) void deg_kernel(const float* __restrict__ W,
                                                  float* __restrict__ dh,
                                                  float* __restrict__ dr) {
    int i = blockIdx.x, t = threadIdx.x;
    const float4* row = (const float4*)(W + (size_t)i * N_);
    float s = 0.f;
    for (int c = t; c < N_ / 4; c += 256) { float4 v = row[c]; s += v.x + v.y + v.z + v.w; }
    __shared__ float red[256];
    red[t] = s; __syncthreads();
    for (int o = 128; o; o >>= 1) { if (t < o) red[t] += red[t + o]; __syncthreads(); }
    if (t == 0) {
        float deg = red[0];
        float dhi = 1.f / sqrtf(fmaxf(deg, 1.f));
        dh[i] = dhi;
        dr[i] = (dhi * dhi * deg - C0_) / H_;
    }
}

// ELL build: all 64 entries pre-filled with (col=i, val=0) pads; cnt rounded up to mult of 8.
__global__ __launch_bounds__(64) void ell_kernel(const float* __restrict__ W,
                                                 const float* __restrict__ dh,
                                                 int* __restrict__ cnt,
                                                 int* __restrict__ cols,
                                                 float* __restrict__ vals) {
    int i = blockIdx.x, lane = threadIdx.x;
    cols[i * ELLW_ + lane] = i;            // pad defaults
    vals[i * ELLW_ + lane] = 0.f;
    __syncthreads();
    const float* row = W + (size_t)i * N_;
    unsigned long long lt = (1ull << lane) - 1ull;
    int base = 0;
    float dhi = dh[i];
    for (int c = 0; c < N_; c += 64) {
        float v = row[c + lane];
        unsigned long long m = __ballot(v != 0.f);
        if (v != 0.f) {
            int pos = base + __popcll(m & lt);
            if (pos < ELLW_) {
                cols[i * ELLW_ + pos] = c + lane;
                vals[i * ELLW_ + pos] = dhi * dh[c + lane] / H_;
            }
        }
        base += __popcll(m);
    }
    if (lane == 0) {
        int n = base < ELLW_ ? base : ELLW_;
        cnt[i] = (n + 7) & ~7;             // padded count (pads are no-ops)
    }
}

// deterministic counting sort of rows by padded degree -> perm
__global__ __launch_bounds__(256) void perm_kernel(const int* __restrict__ cnt,
                                                   int* __restrict__ perm) {
    __shared__ int sb[N_];                 // 8 KB: bucket id per row
    __shared__ int bstart[9];
    int t = threadIdx.x;
    for (int i = t; i < N_; i += 256) sb[i] = cnt[i] >> 3;   // 0..8
    __syncthreads();
    if (t == 0) {
        int h[9] = {0, 0, 0, 0, 0, 0, 0, 0, 0};
        for (int i = 0; i < N_; ++i) h[sb[i]]++;
        int acc = 0;
        for (int b = 0; b < 9; ++b) { bstart[b] = acc; acc += h[b]; }
    }
    __syncthreads();
    for (int i = t; i < N_; i += 256) {
        int b = sb[i], r = 0;
        for (int k = 0; k < i; ++k) r += (sb[k] == b);       // stable rank
        perm[bstart[b] + r] = i;
    }
}

// parallel DCT: one block per filter j
__global__ __launch_bounds__(256) void coef_kernel(float* __restrict__ coefs) {
    __shared__ float fv[M_];
    int j = blockIdx.x;
    int t = threadIdx.x;
    float theta = PI_F * (t + 0.5f) / M_;
    fv[t] = filter_eval(C0_ + H_ * cosf(theta), j);
    __syncthreads();
    float s = 0.f;
    for (int i = 0; i < M_; ++i)
        s += fv[i] * cosf(PI_F * t * (i + 0.5f) / M_);
    coefs[j * M_ + t] = s * ((t == 0 ? 1.f : 2.f) / M_);
}

// slot0 = I (fp16), slot1 = scaled L-tilde (fp16)
__global__ __launch_bounds__(256) void init_slots(__half* __restrict__ S0, __half* __restrict__ S1,
                                                  const int* __restrict__ cnt, const int* __restrict__ cols,
                                                  const float* __restrict__ vals, const float* __restrict__ dr) {
    int i = blockIdx.x, t = threadIdx.x;
    size_t ro = (size_t)i * N_;
    for (int c = t * 8; c < N_; c += 2048) {
        *(uint4*)(S0 + ro + c) = uint4{0, 0, 0, 0};
        *(uint4*)(S1 + ro + c) = uint4{0, 0, 0, 0};
    }
    __syncthreads();
    int n = cnt[i];
    if (t < n) {
        int c = cols[i * ELLW_ + t];
        float v = -vals[i * ELLW_ + t];
        if (v != 0.f) S1[ro + c] = __float2half(v);   // skip pads (col=i, val=0)
    }
    __syncthreads();
    if (t == 0) {
        S0[ro + i] = __float2half(1.f);
        S1[ro + i] = __float2half(dr[i]);
    }
}

// ------- Chebyshev step, XCD-striped + degree-sorted rows ----------
// blockIdx.x & 7 = column stripe (256 cols) -> one XCD via round-robin dispatch;
// rows processed in degree-sorted order (perm) so the 2 rows of each wave match.
__global__ __launch_bounds__(256) void cheb_fp16(const __half* __restrict__ X,
                                                 const __half* __restrict__ Tprev,
                                                 __half* __restrict__ Tnext,
                                                 const int* __restrict__ cnt,
                                                 const int* __restrict__ cols,
                                                 const float* __restrict__ vals,
                                                 const float* __restrict__ dr,
                                                 const int* __restrict__ perm) {
    int strp = blockIdx.x & 7;
    int rg   = blockIdx.x >> 3;
    int tr   = threadIdx.x >> 5;           // 0..7: row within block
    int lr   = threadIdx.x & 31;
    __shared__ int   sperm[8];
    __shared__ int   scnt[8];
    __shared__ int   scols[8][ELLW_];
    __shared__ float svals[8][ELLW_];
    if (threadIdx.x < 8) {
        int p = perm[rg * 8 + threadIdx.x];
        sperm[threadIdx.x] = p;
        scnt[threadIdx.x]  = cnt[p];
    }
    __syncthreads();
    {
        int e = threadIdx.x & 63, r0 = threadIdx.x >> 6;      // r0 in 0..3
        int p0 = sperm[r0], p1 = sperm[r0 + 4];
        scols[r0][e] = cols[p0 * ELLW_ + e];     svals[r0][e] = vals[p0 * ELLW_ + e];
        scols[r0 + 4][e] = cols[p1 * ELLW_ + e]; svals[r0 + 4][e] = vals[p1 * ELLW_ + e];
    }
    __syncthreads();
    int i   = sperm[tr];
    int n   = scnt[tr];                      // multiple of 8 (or 0)
    int col = strp * 256 + lr * 8;
    float a[8] = {0, 0, 0, 0, 0, 0, 0, 0};
    for (int e0 = 0; e0 < n; e0 += 8) {
        uint4 q[8];
        float v[8];
#pragma unroll
        for (int u = 0; u < 8; ++u) {
            int c = scols[tr][e0 + u];
            v[u] = svals[tr][e0 + u];
            q[u] = *(const uint4*)(X + (size_t)c * N_ + col);
        }
#pragma unroll
        for (int u = 0; u < 8; ++u) {
            const __half2* h = (const __half2*)&q[u];
            float2 f0 = __half22float2(h[0]), f1 = __half22float2(h[1]);
            float2 f2 = __half22float2(h[2]), f3 = __half22float2(h[3]);
            a[0] -= v[u] * f0.x; a[1] -= v[u] * f0.y;
            a[2] -= v[u] * f1.x; a[3] -= v[u] * f1.y;
            a[4] -= v[u] * f2.x; a[5] -= v[u] * f2.y;
            a[6] -= v[u] * f3.x; a[7] -= v[u] * f3.y;
        }
    }
    size_t po = (size_t)i * N_ + col;
    {   // diagonal term
        float d = dr[i];
        uint4 q = *(const uint4*)(X + po);
        const __half2* h = (const __half2*)&q;
        float2 f0 = __half22float2(h[0]), f1 = __half22float2(h[1]);
        float2 f2 = __half22float2(h[2]), f3 = __half22float2(h[3]);
        a[0] += d * f0.x; a[1] += d * f0.y; a[2] += d * f1.x; a[3] += d * f1.y;
        a[4] += d * f2.x; a[5] += d * f2.y; a[6] += d * f3.x; a[7] += d * f3.y;
    }
    uint4 qp = *(const uint4*)(Tprev + po);
    const __half2* hp = (const __half2*)&qp;
    float2 p0 = __half22float2(hp[0]), p1 = __half22float2(hp[1]);
    float2 p2 = __half22float2(hp[2]), p3 = __half22float2(hp[3]);
    __half2 s0 = __floats2half2_rn(2.f * a[0] - p0.x, 2.f * a[1] - p0.y);
    __half2 s1 = __floats2half2_rn(2.f * a[2] - p1.x, 2.f * a[3] - p1.y);
    __half2 s2 = __floats2half2_rn(2.f * a[4] - p2.x, 2.f * a[5] - p2.y);
    __half2 s3 = __floats2half2_rn(2.f * a[6] - p3.x, 2.f * a[7] - p3.y);
    uint4 sq;
    sq.x = *(const unsigned int*)&s0; sq.y = *(const unsigned int*)&s1;
    sq.z = *(const unsigned int*)&s2; sq.w = *(const unsigned int*)&s3;
    *(uint4*)(Tnext + po) = sq;
}

// ---------------- group reduction: Gh_j += sum_{k in [k0,k0+nslot)} b_{jk} * slot(k%g) -------
__global__ __launch_bounds__(256) void reduce_half(const __half* __restrict__ slots,
                                                   int g, int k0, int nslot, int initG,
                                                   const float* __restrict__ coefs,
                                                   __half* __restrict__ Gh) {
    const size_t NSQ = (size_t)N_ * N_;
    size_t idx = ((size_t)blockIdx.x * 256 + threadIdx.x) * 8;
    __shared__ float sc[J_ * 64];
    for (int x = threadIdx.x; x < J_ * nslot; x += 256) {
        int j = x / nslot, s = x - j * nslot;
        sc[j * 64 + s] = coefs[j * M_ + k0 + s];
    }
    __syncthreads();
    float acc[J_][8];
#pragma unroll
    for (int j = 0; j < J_; ++j) {
        if (initG) {
#pragma unroll
            for (int r = 0; r < 8; ++r) acc[j][r] = 0.f;
        } else {
            uint4 q = *(const uint4*)(Gh + (size_t)j * NSQ + idx);
            const __half2* h = (const __half2*)&q;
            float2 f0 = __half22float2(h[0]), f1 = __half22float2(h[1]);
            float2 f2 = __half22float2(h[2]), f3 = __half22float2(h[3]);
            acc[j][0] = f0.x; acc[j][1] = f0.y; acc[j][2] = f1.x; acc[j][3] = f1.y;
            acc[j][4] = f2.x; acc[j][5] = f2.y; acc[j][6] = f3.x; acc[j][7] = f3.y;
        }
    }
    for (int s = 0; s < nslot; ++s) {
        int slot = (k0 + s) % g;
        uint4 q = *(const uint4*)(slots + (size_t)slot * NSQ + idx);
        const __half2* h = (const __half2*)&q;
        float2 f0 = __half22float2(h[0]), f1 = __half22float2(h[1]);
        float2 f2 = __half22float2(h[2]), f3 = __half22float2(h[3]);
        float f[8] = {f0.x, f0.y, f1.x, f1.y, f2.x, f2.y, f3.x, f3.y};
#pragma unroll
        for (int j = 0; j < J_; ++j) {
            float c = sc[j * 64 + s];
#pragma unroll
            for (int r = 0; r < 8; ++r) acc[j][r] += c * f[r];
        }
    }
#pragma unroll
    for (int j = 0; j < J_; ++j) {
        __half2 o0 = __floats2half2_rn(acc[j][0], acc[j][1]);
        __half2 o1 = __floats2half2_rn(acc[j][2], acc[j][3]);
        __half2 o2 = __floats2half2_rn(acc[j][4], acc[j][5]);
        __half2 o3 = __floats2half2_rn(acc[j][6], acc[j][7]);
        uint4 o;
        o.x = *(const unsigned int*)&o0; o.y = *(const unsigned int*)&o1;
        o.z = *(const unsigned int*)&o2; o.w = *(const unsigned int*)&o3;
        *(uint4*)(Gh + (size_t)j * NSQ + idx) = o;
    }
}

// ---------------- f [2048][256] f32  ->  fhT [256][2048] f16 (transposed) ----------------
__global__ __launch_bounds__(256) void transpose_f16(const float* __restrict__ src,
                                                     __half* __restrict__ dst) {
    int d = blockIdx.x;                    // 256 output rows
    int i0 = threadIdx.x * 8;              // 8 nodes per thread
    __half h[8];
#pragma unroll
    for (int u = 0; u < 8; ++u) h[u] = __float2half(src[(size_t)(i0 + u) * DF_ + d]);
    uint4 o;
    __half2* hp = (__half2*)&o;
    hp[0] = __half2{h[0], h[1]}; hp[1] = __half2{h[2], h[3]};
    hp[2] = __half2{h[4], h[5]}; hp[3] = __half2{h[6], h[7]};
    *(uint4*)(dst + (size_t)d * N_ + i0) = o;
}

// ---------------- MFMA fp16 GEMM, both operands k-major, XOR-swizzled LDS --------------
// C = Gh[16384 x 2048] * BT^T.  BT rows are k-major length 2048.
// MODE 0: BT = fhT [256][2048]; writes U1T [2048 cols][2048 nodes] + colsum1[j*256+d].
// MODE 1: BT = U1T [2048][2048]; colsum2[(b*8+j)*256+d].
template <int MODE>
__global__ __launch_bounds__(256) void mfma_gemm(const __half* __restrict__ A,
                                                 const __half* __restrict__ BT,
                                                 __half* __restrict__ U1T,
                                                 float* __restrict__ colsum) {
    __shared__ u16 As[128 * 64];
    __shared__ u16 Bs[128 * 64];
    int tid = threadIdx.x;
    int w = tid >> 6, lane = tid & 63;
    int wr = w >> 1, wc = w & 1;
    int gm0 = blockIdx.y * 128, n0 = blockIdx.x * 128;
    f32x4 acc[4][4];
#pragma unroll
    for (int mf = 0; mf < 4; ++mf)
#pragma unroll
        for (int nf = 0; nf < 4; ++nf) acc[mf][nf] = (f32x4){0.f, 0.f, 0.f, 0.f};

    int r = tid >> 1, h = tid & 1;         // 128 rows, 2 threads/row (32 u16 each)
    int sw = r & 7;
    for (int k0 = 0; k0 < 2048; k0 += 64) {
        const u16* ap = (const u16*)A + (size_t)(gm0 + r) * 2048 + k0 + h * 32;
        const u16* bp = (const u16*)BT + (size_t)(n0 + r) * 2048 + k0 + h * 32;
#pragma unroll
        for (int q = 0; q < 4; ++q) {
            int blk = (h * 4 + q) ^ sw;    // XOR swizzle in 8-u16 (16B) granules
            *(uint4*)(As + r * 64 + blk * 8) = *(const uint4*)(ap + q * 8);
            *(uint4*)(Bs + r * 64 + blk * 8) = *(const uint4*)(bp + q * 8);
        }
        __syncthreads();
#pragma unroll
        for (int s = 0; s < 2; ++s) {
            f16x8 af[4], bfv[4];
#pragma unroll
            for (int mf = 0; mf < 4; ++mf) {
                int row = wr * 64 + mf * 16 + (lane & 15);
                int blk = (s * 4 + (lane >> 4)) ^ (row & 7);
                af[mf] = *(const f16x8*)(As + row * 64 + blk * 8);
            }
#pragma unroll
            for (int nf = 0; nf < 4; ++nf) {
                int row = wc * 64 + nf * 16 + (lane & 15);
                int blk = (s * 4 + (lane >> 4)) ^ (row & 7);
                bfv[nf] = *(const f16x8*)(Bs + row * 64 + blk * 8);
            }
#pragma unroll
            for (int mf = 0; mf < 4; ++mf)
#pragma unroll
                for (int nf = 0; nf < 4; ++nf)
                    acc[mf][nf] = __builtin_amdgcn_mfma_f32_16x16x32_f16(
                        af[mf], bfv[nf], acc[mf][nf], 0, 0, 0);
        }
        __syncthreads();
    }
    // epilogue: C frag layout col = lane&15, row = (lane>>4)*4 + reg
    int j = gm0 >> 11;
    int ibase = (gm0 & (N_ - 1)) + wr * 64 + (lane >> 4) * 4;
#pragma unroll
    for (int nf = 0; nf < 4; ++nf) {
        int d = n0 + wc * 64 + nf * 16 + (lane & 15);
        float cs = 0.f;
#pragma unroll
        for (int mf = 0; mf < 4; ++mf) {
            float v0 = fabsf(acc[mf][nf][0]);
            float v1 = fabsf(acc[mf][nf][1]);
            float v2 = fabsf(acc[mf][nf][2]);
            float v3 = fabsf(acc[mf][nf][3]);
            cs += v0 + v1 + v2 + v3;
            if (MODE == 0) {
                ushort4 o;
                o.x = __half_as_ushort(__float2half(v0));
                o.y = __half_as_ushort(__float2half(v1));
                o.z = __half_as_ushort(__float2half(v2));
                o.w = __half_as_ushort(__float2half(v3));
                *(ushort4*)(U1T + (size_t)(j * 256 + d) * N_ + ibase + mf * 16) = o;
            }
        }
        cs += __shfl_xor(cs, 16);
        cs += __shfl_xor(cs, 32);
        if ((lane >> 4) == 0) {
            int colg = n0 + wc * 64 + nf * 16 + lane;
            if (MODE == 0) atomicAdd(&colsum[j * 256 + colg], cs);
            else atomicAdd(&colsum[(((colg >> 8) * 8 + j) << 8) + (colg & 255)], cs);
        }
    }
}

__global__ __launch_bounds__(256) void fmean_kernel(const float* __restrict__ f, float* __restrict__ out) {
    int d = blockIdx.x, t = threadIdx.x;
    float s = 0.f;
    for (int n = t; n < N_; n += 256) s += f[(size_t)n * DF_ + d];
    __shared__ float red[256];
    red[t] = s; __syncthreads();
    for (int o = 128; o; o >>= 1) { if (t < o) red[t] += red[t + o]; __syncthreads(); }
    if (t == 0) out[d] = red[0] * (1.f / N_);
}

__global__ __launch_bounds__(256) void finalize_kernel(const float* __restrict__ sum1,
                                                       const float* __restrict__ sum2,
                                                       float* __restrict__ out) {
    int idx = blockIdx.x * 256 + threadIdx.x;
    if (idx < 2048)  out[256 + idx]  = sum1[idx] * (1.f / N_);
    if (idx < 16384) out[2304 + idx] = sum2[idx] * (1.f / N_);
}

// ---------------- host orchestration ----------------
extern "C" void kernel_launch(void* const* d_in, const int* in_sizes, int n_in,
                              void* d_out, int out_size, void* d_ws, size_t ws_size,
                              hipStream_t stream) {
    (void)in_sizes; (void)n_in;
    const float* W = (const float*)d_in[0];
    const float* f = (const float*)d_in[1];
    float* out = (float*)d_out;
    char* base = (char*)d_ws;
    size_t off = 0;
    auto take = [&](size_t bytes) -> char* {
        off = (off + 255) & ~(size_t)255;
        char* p = base + off; off += bytes; return p;
    };
    const size_t NSQ = (size_t)N_ * N_;
    float*  dh    = (float*)take((size_t)N_ * 4);
    float*  dr    = (float*)take((size_t)N_ * 4);
    int*    cnt   = (int*)take((size_t)N_ * 4);
    int*    perm  = (int*)take((size_t)N_ * 4);
    int*    cols  = (int*)take((size_t)N_ * ELLW_ * 4);
    float*  vals  = (float*)take((size_t)N_ * ELLW_ * 4);
    float*  coefs = (float*)take((size_t)J_ * M_ * 4);
    float*  sum1  = (float*)take(2048 * 4);
    float*  sum2  = (float*)take(16384 * 4);
    __half* Gh    = (__half*)take(NSQ * 2 * J_);                 //  67.1 MB
    __half* U1T   = (__half*)take((size_t)N_ * 2048 * 2);        //   8.4 MB
    __half* fhT   = (__half*)take((size_t)N_ * DF_ * 2);         //   1.0 MB
    off = (off + 255) & ~(size_t)255;
    const size_t slotBytes = NSQ * 2;
    long long rem = (long long)ws_size - (long long)off;
    int g = (int)(rem / (long long)slotBytes);
    if (g > GCAP_) g = GCAP_;
    if (g < 3) {                       // workspace too small — cannot run
        hipMemsetAsync(d_out, 0, (size_t)out_size * 4, stream);
        return;
    }
    __half* slots = (__half*)take((size_t)g * slotBytes);

    deg_kernel<<<N_, 256, 0, stream>>>(W, dh, dr);
    ell_kernel<<<N_, 64, 0, stream>>>(W, dh, cnt, cols, vals);
    perm_kernel<<<1, 256, 0, stream>>>(cnt, perm);
    coef_kernel<<<J_, 256, 0, stream>>>(coefs);
    hipMemsetAsync(sum1, 0, 2048 * 4, stream);
    hipMemsetAsync(sum2, 0, 16384 * 4, stream);
    init_slots<<<N_, 256, 0, stream>>>(slots, slots + NSQ, cnt, cols, vals, dr);

    int k0 = 0;                        // start of current un-reduced group
    for (int k = 2; k < MUSE_; ++k) {
        cheb_fp16<<<2048, 256, 0, stream>>>(
            slots + (size_t)((k - 1) % g) * NSQ,
            slots + (size_t)((k - 2) % g) * NSQ,
            slots + (size_t)(k % g) * NSQ,
            cnt, cols, vals, dr, perm);
        if (k - k0 + 1 == g || k == MUSE_ - 1) {
            reduce_half<<<2048, 256, 0, stream>>>(slots, g, k0, k - k0 + 1,
                                                  k0 == 0 ? 1 : 0, coefs, Gh);
            k0 = k + 1;
        }
    }
    transpose_f16<<<DF_, 256, 0, stream>>>(f, fhT);
    mfma_gemm<0><<<dim3(2, 128), 256, 0, stream>>>(Gh, fhT, U1T, sum1);
    mfma_gemm<1><<<dim3(16, 128), 256, 0, stream>>>(Gh, U1T, (__half*)nullptr, sum2);
    fmean_kernel<<<DF_, 256, 0, stream>>>(f, out);
    finalize_kernel<<<64, 256, 0, stream>>>(sum1, sum2, out);
}

// Round 8
// 1715.713 us; speedup vs baseline: 11.9764x; 1.2414x over previous
//
#include <hip/hip_runtime.h>
#include <hip/hip_fp16.h>
#include <math.h>

// ---------------- constants ----------------
constexpr int   N_   = 2048;
constexpr int   DF_  = 256;
constexpr int   J_   = 8;
constexpr int   ELLW_= 64;
constexpr int   M_   = 256;          // coefficient array stride (256-pt DCT quadrature)
constexpr int   MUSE_= 96;           // Chebyshev terms actually used (degree 95)
constexpr int   GCAP_= 20;           // slot ring size cap (slots+Gh fit 256MB L3)
constexpr float H_   = 1.01f;        // domain half-width  ([-0.01, 2.01])
constexpr float C0_  = 1.0f;         // domain center
constexpr float AF_  = 0.34657359027997264f;   // A = 3*ln(2)/6
constexpr float PI_F = 3.14159265358979323846f;

typedef _Float16 f16x8 __attribute__((ext_vector_type(8)));
typedef __attribute__((ext_vector_type(4))) float f32x4;
using u16 = unsigned short;

// ---------------- filter functions ----------------
__device__ __forceinline__ float g_hat_f(float x) {
    float val = 0.5f + 0.5f * cosf(2.f * PI_F * (x / AF_ + 0.5f));
    return (x <= 0.f && x > -AF_) ? val : 0.f;
}
__device__ __forceinline__ float wavelet_f(float lamb, int j) {
    float lmin = expf(AF_ * ((j - 1) / 3.0f - 1.0f));
    float lam  = fmaxf(lamb, lmin);
    return g_hat_f(logf(lam) - AF_ * (j - 1) / 3.0f);
}
__device__ __forceinline__ float filter_eval(float lamb, int jf) {
    if (jf == 0) {
        float g3 = 0.f;
        for (int j = 2; j <= 8; ++j) { float w = wavelet_f(lamb, j); g3 += w * w; }
        return sqrtf(fmaxf(1.5f - g3, 0.f));
    }
    return wavelet_f(lamb, jf + 1);
}

// ---------------- setup kernels ----------------
__global__ __launch_bounds__(256) void deg_kernel(const float* __restrict__ W,
                                                  float* __restrict__ dh,
                                                  float* __restrict__ dr) {
    int i = blockIdx.x, t = threadIdx.x;
    const float4* row = (const float4*)(W + (size_t)i * N_);
    float s = 0.f;
    for (int c = t; c < N_ / 4; c += 256) { float4 v = row[c]; s += v.x + v.y + v.z + v.w; }
    __shared__ float red[256];
    red[t] = s; __syncthreads();
    for (int o = 128; o; o >>= 1) { if (t < o) red[t] += red[t + o]; __syncthreads(); }
    if (t == 0) {
        float deg = red[0];
        float dhi = 1.f / sqrtf(fmaxf(deg, 1.f));
        dh[i] = dhi;
        dr[i] = (dhi * dhi * deg - C0_) / H_;
    }
}

// ELL build: all 64 entries pre-filled with (col=i, val=0) pads; cnt rounded up to mult of 8.
__global__ __launch_bounds__(64) void ell_kernel(const float* __restrict__ W,
                                                 const float* __restrict__ dh,
                                                 int* __restrict__ cnt,
                                                 int* __restrict__ cols,
                                                 float* __restrict__ vals) {
    int i = blockIdx.x, lane = threadIdx.x;
    cols[i * ELLW_ + lane] = i;            // pad defaults
    vals[i * ELLW_ + lane] = 0.f;
    __syncthreads();
    const float* row = W + (size_t)i * N_;
    unsigned long long lt = (1ull << lane) - 1ull;
    int base = 0;
    float dhi = dh[i];
    for (int c = 0; c < N_; c += 64) {
        float v = row[c + lane];
        unsigned long long m = __ballot(v != 0.f);
        if (v != 0.f) {
            int pos = base + __popcll(m & lt);
            if (pos < ELLW_) {
                cols[i * ELLW_ + pos] = c + lane;
                vals[i * ELLW_ + pos] = dhi * dh[c + lane] / H_;
            }
        }
        base += __popcll(m);
    }
    if (lane == 0) {
        int n = base < ELLW_ ? base : ELLW_;
        cnt[i] = (n + 7) & ~7;             // padded count (pads are no-ops)
    }
}

// deterministic counting sort of rows by padded degree -> perm (parallel scan version)
__global__ __launch_bounds__(256) void perm_kernel(const int* __restrict__ cnt,
                                                   int* __restrict__ perm) {
    __shared__ int hist[9][256];           // per-thread bucket counts -> exclusive offsets
    __shared__ int bstart[9];
    int t = threadIdx.x;
    int b[8];
    int h[9] = {0, 0, 0, 0, 0, 0, 0, 0, 0};
#pragma unroll
    for (int u = 0; u < 8; ++u) {
        b[u] = cnt[t * 8 + u] >> 3;        // bucket 0..8
        h[b[u]]++;
    }
#pragma unroll
    for (int bb = 0; bb < 9; ++bb) hist[bb][t] = h[bb];
    __syncthreads();
    if (t < 9) {                           // exclusive scan across threads, per bucket
        int acc = 0;
        for (int k = 0; k < 256; ++k) { int v = hist[t][k]; hist[t][k] = acc; acc += v; }
        bstart[t] = acc;                   // bucket total
    }
    __syncthreads();
    if (t == 0) {                          // exclusive scan of bucket totals
        int acc = 0;
        for (int bb = 0; bb < 9; ++bb) { int v = bstart[bb]; bstart[bb] = acc; acc += v; }
    }
    __syncthreads();
    int run[9] = {0, 0, 0, 0, 0, 0, 0, 0, 0};
#pragma unroll
    for (int u = 0; u < 8; ++u) {
        int bb = b[u];
        perm[bstart[bb] + hist[bb][t] + run[bb]] = t * 8 + u;
        run[bb]++;
    }
}

// parallel DCT: one block per filter j
__global__ __launch_bounds__(256) void coef_kernel(float* __restrict__ coefs) {
    __shared__ float fv[M_];
    int j = blockIdx.x;
    int t = threadIdx.x;
    float theta = PI_F * (t + 0.5f) / M_;
    fv[t] = filter_eval(C0_ + H_ * cosf(theta), j);
    __syncthreads();
    float s = 0.f;
    for (int i = 0; i < M_; ++i)
        s += fv[i] * cosf(PI_F * t * (i + 0.5f) / M_);
    coefs[j * M_ + t] = s * ((t == 0 ? 1.f : 2.f) / M_);
}

// slot0 = I (fp16), slot1 = scaled L-tilde (fp16)
__global__ __launch_bounds__(256) void init_slots(__half* __restrict__ S0, __half* __restrict__ S1,
                                                  const int* __restrict__ cnt, const int* __restrict__ cols,
                                                  const float* __restrict__ vals, const float* __restrict__ dr) {
    int i = blockIdx.x, t = threadIdx.x;
    size_t ro = (size_t)i * N_;
    for (int c = t * 8; c < N_; c += 2048) {
        *(uint4*)(S0 + ro + c) = uint4{0, 0, 0, 0};
        *(uint4*)(S1 + ro + c) = uint4{0, 0, 0, 0};
    }
    __syncthreads();
    int n = cnt[i];
    if (t < n) {
        int c = cols[i * ELLW_ + t];
        float v = -vals[i * ELLW_ + t];
        if (v != 0.f) S1[ro + c] = __float2half(v);   // skip pads (col=i, val=0)
    }
    __syncthreads();
    if (t == 0) {
        S0[ro + i] = __float2half(1.f);
        S1[ro + i] = __float2half(dr[i]);
    }
}

// ------- Chebyshev step, XCD-striped + degree-sorted rows ----------
// blockIdx.x & 7 = column stripe (256 cols) -> one XCD via round-robin dispatch;
// rows processed in degree-sorted order (perm) so the 2 rows of each wave match.
__global__ __launch_bounds__(256) void cheb_fp16(const __half* __restrict__ X,
                                                 const __half* __restrict__ Tprev,
                                                 __half* __restrict__ Tnext,
                                                 const int* __restrict__ cnt,
                                                 const int* __restrict__ cols,
                                                 const float* __restrict__ vals,
                                                 const float* __restrict__ dr,
                                                 const int* __restrict__ perm) {
    int strp = blockIdx.x & 7;
    int rg   = blockIdx.x >> 3;
    int tr   = threadIdx.x >> 5;           // 0..7: row within block
    int lr   = threadIdx.x & 31;
    __shared__ int   sperm[8];
    __shared__ int   scnt[8];
    __shared__ int   scols[8][ELLW_];
    __shared__ float svals[8][ELLW_];
    if (threadIdx.x < 8) {
        int p = perm[rg * 8 + threadIdx.x];
        sperm[threadIdx.x] = p;
        scnt[threadIdx.x]  = cnt[p];
    }
    __syncthreads();
    {
        int e = threadIdx.x & 63, r0 = threadIdx.x >> 6;      // r0 in 0..3
        int p0 = sperm[r0], p1 = sperm[r0 + 4];
        scols[r0][e] = cols[p0 * ELLW_ + e];     svals[r0][e] = vals[p0 * ELLW_ + e];
        scols[r0 + 4][e] = cols[p1 * ELLW_ + e]; svals[r0 + 4][e] = vals[p1 * ELLW_ + e];
    }
    __syncthreads();
    int i   = sperm[tr];
    int n   = scnt[tr];                      // multiple of 8 (or 0)
    int col = strp * 256 + lr * 8;
    float a[8] = {0, 0, 0, 0, 0, 0, 0, 0};
    for (int e0 = 0; e0 < n; e0 += 8) {
        uint4 q[8];
        float v[8];
#pragma unroll
        for (int u = 0; u < 8; ++u) {
            int c = scols[tr][e0 + u];
            v[u] = svals[tr][e0 + u];
            q[u] = *(const uint4*)(X + (size_t)c * N_ + col);
        }
#pragma unroll
        for (int u = 0; u < 8; ++u) {
            const __half2* h = (const __half2*)&q[u];
            float2 f0 = __half22float2(h[0]), f1 = __half22float2(h[1]);
            float2 f2 = __half22float2(h[2]), f3 = __half22float2(h[3]);
            a[0] -= v[u] * f0.x; a[1] -= v[u] * f0.y;
            a[2] -= v[u] * f1.x; a[3] -= v[u] * f1.y;
            a[4] -= v[u] * f2.x; a[5] -= v[u] * f2.y;
            a[6] -= v[u] * f3.x; a[7] -= v[u] * f3.y;
        }
    }
    size_t po = (size_t)i * N_ + col;
    {   // diagonal term
        float d = dr[i];
        uint4 q = *(const uint4*)(X + po);
        const __half2* h = (const __half2*)&q;
        float2 f0 = __half22float2(h[0]), f1 = __half22float2(h[1]);
        float2 f2 = __half22float2(h[2]), f3 = __half22float2(h[3]);
        a[0] += d * f0.x; a[1] += d * f0.y; a[2] += d * f1.x; a[3] += d * f1.y;
        a[4] += d * f2.x; a[5] += d * f2.y; a[6] += d * f3.x; a[7] += d * f3.y;
    }
    uint4 qp = *(const uint4*)(Tprev + po);
    const __half2* hp = (const __half2*)&qp;
    float2 p0 = __half22float2(hp[0]), p1 = __half22float2(hp[1]);
    float2 p2 = __half22float2(hp[2]), p3 = __half22float2(hp[3]);
    __half2 s0 = __floats2half2_rn(2.f * a[0] - p0.x, 2.f * a[1] - p0.y);
    __half2 s1 = __floats2half2_rn(2.f * a[2] - p1.x, 2.f * a[3] - p1.y);
    __half2 s2 = __floats2half2_rn(2.f * a[4] - p2.x, 2.f * a[5] - p2.y);
    __half2 s3 = __floats2half2_rn(2.f * a[6] - p3.x, 2.f * a[7] - p3.y);
    uint4 sq;
    sq.x = *(const unsigned int*)&s0; sq.y = *(const unsigned int*)&s1;
    sq.z = *(const unsigned int*)&s2; sq.w = *(const unsigned int*)&s3;
    *(uint4*)(Tnext + po) = sq;
}

// ---------------- group reduction: Gh_j += sum_{k in [k0,k0+nslot)} b_{jk} * slot(k%g) -------
__global__ __launch_bounds__(256) void reduce_half(const __half* __restrict__ slots,
                                                   int g, int k0, int nslot, int initG,
                                                   const float* __restrict__ coefs,
                                                   __half* __restrict__ Gh) {
    const size_t NSQ = (size_t)N_ * N_;
    size_t idx = ((size_t)blockIdx.x * 256 + threadIdx.x) * 8;
    __shared__ float sc[J_ * 64];
    for (int x = threadIdx.x; x < J_ * nslot; x += 256) {
        int j = x / nslot, s = x - j * nslot;
        sc[j * 64 + s] = coefs[j * M_ + k0 + s];
    }
    __syncthreads();
    float acc[J_][8];
#pragma unroll
    for (int j = 0; j < J_; ++j) {
        if (initG) {
#pragma unroll
            for (int r = 0; r < 8; ++r) acc[j][r] = 0.f;
        } else {
            uint4 q = *(const uint4*)(Gh + (size_t)j * NSQ + idx);
            const __half2* h = (const __half2*)&q;
            float2 f0 = __half22float2(h[0]), f1 = __half22float2(h[1]);
            float2 f2 = __half22float2(h[2]), f3 = __half22float2(h[3]);
            acc[j][0] = f0.x; acc[j][1] = f0.y; acc[j][2] = f1.x; acc[j][3] = f1.y;
            acc[j][4] = f2.x; acc[j][5] = f2.y; acc[j][6] = f3.x; acc[j][7] = f3.y;
        }
    }
    for (int s = 0; s < nslot; ++s) {
        int slot = (k0 + s) % g;
        uint4 q = *(const uint4*)(slots + (size_t)slot * NSQ + idx);
        const __half2* h = (const __half2*)&q;
        float2 f0 = __half22float2(h[0]), f1 = __half22float2(h[1]);
        float2 f2 = __half22float2(h[2]), f3 = __half22float2(h[3]);
        float f[8] = {f0.x, f0.y, f1.x, f1.y, f2.x, f2.y, f3.x, f3.y};
#pragma unroll
        for (int j = 0; j < J_; ++j) {
            float c = sc[j * 64 + s];
#pragma unroll
            for (int r = 0; r < 8; ++r) acc[j][r] += c * f[r];
        }
    }
#pragma unroll
    for (int j = 0; j < J_; ++j) {
        __half2 o0 = __floats2half2_rn(acc[j][0], acc[j][1]);
        __half2 o1 = __floats2half2_rn(acc[j][2], acc[j][3]);
        __half2 o2 = __floats2half2_rn(acc[j][4], acc[j][5]);
        __half2 o3 = __floats2half2_rn(acc[j][6], acc[j][7]);
        uint4 o;
        o.x = *(const unsigned int*)&o0; o.y = *(const unsigned int*)&o1;
        o.z = *(const unsigned int*)&o2; o.w = *(const unsigned int*)&o3;
        *(uint4*)(Gh + (size_t)j * NSQ + idx) = o;
    }
}

// ---------------- f [2048][256] f32  ->  fhT [256][2048] f16 (transposed) ----------------
__global__ __launch_bounds__(256) void transpose_f16(const float* __restrict__ src,
                                                     __half* __restrict__ dst) {
    int d = blockIdx.x;                    // 256 output rows
    int i0 = threadIdx.x * 8;              // 8 nodes per thread
    __half h[8];
#pragma unroll
    for (int u = 0; u < 8; ++u) h[u] = __float2half(src[(size_t)(i0 + u) * DF_ + d]);
    uint4 o;
    __half2* hp = (__half2*)&o;
    hp[0] = __half2{h[0], h[1]}; hp[1] = __half2{h[2], h[3]};
    hp[2] = __half2{h[4], h[5]}; hp[3] = __half2{h[6], h[7]};
    *(uint4*)(dst + (size_t)d * N_ + i0) = o;
}

// ---------------- MFMA fp16 GEMM, both operands k-major, XOR-swizzled LDS --------------
// C = Gh[16384 x 2048] * BT^T.  BT rows are k-major length 2048.
// MODE 0: BT = fhT [256][2048]; writes U1T [2048 cols][2048 nodes] + colsum1[j*256+d].
// MODE 1: BT = U1T [2048][2048]; colsum2[(b*8+j)*256+d].
template <int MODE>
__global__ __launch_bounds__(256) void mfma_gemm(const __half* __restrict__ A,
                                                 const __half* __restrict__ BT,
                                                 __half* __restrict__ U1T,
                                                 float* __restrict__ colsum) {
    __shared__ u16 As[128 * 64];
    __shared__ u16 Bs[128 * 64];
    int tid = threadIdx.x;
    int w = tid >> 6, lane = tid & 63;
    int wr = w >> 1, wc = w & 1;
    int gm0 = blockIdx.y * 128, n0 = blockIdx.x * 128;
    f32x4 acc[4][4];
#pragma unroll
    for (int mf = 0; mf < 4; ++mf)
#pragma unroll
        for (int nf = 0; nf < 4; ++nf) acc[mf][nf] = (f32x4){0.f, 0.f, 0.f, 0.f};

    int r = tid >> 1, h = tid & 1;         // 128 rows, 2 threads/row (32 u16 each)
    int sw = r & 7;
    for (int k0 = 0; k0 < 2048; k0 += 64) {
        const u16* ap = (const u16*)A + (size_t)(gm0 + r) * 2048 + k0 + h * 32;
        const u16* bp = (const u16*)BT + (size_t)(n0 + r) * 2048 + k0 + h * 32;
#pragma unroll
        for (int q = 0; q < 4; ++q) {
            int blk = (h * 4 + q) ^ sw;    // XOR swizzle in 8-u16 (16B) granules
            *(uint4*)(As + r * 64 + blk * 8) = *(const uint4*)(ap + q * 8);
            *(uint4*)(Bs + r * 64 + blk * 8) = *(const uint4*)(bp + q * 8);
        }
        __syncthreads();
#pragma unroll
        for (int s = 0; s < 2; ++s) {
            f16x8 af[4], bfv[4];
#pragma unroll
            for (int mf = 0; mf < 4; ++mf) {
                int row = wr * 64 + mf * 16 + (lane & 15);
                int blk = (s * 4 + (lane >> 4)) ^ (row & 7);
                af[mf] = *(const f16x8*)(As + row * 64 + blk * 8);
            }
#pragma unroll
            for (int nf = 0; nf < 4; ++nf) {
                int row = wc * 64 + nf * 16 + (lane & 15);
                int blk = (s * 4 + (lane >> 4)) ^ (row & 7);
                bfv[nf] = *(const f16x8*)(Bs + row * 64 + blk * 8);
            }
#pragma unroll
            for (int mf = 0; mf < 4; ++mf)
#pragma unroll
                for (int nf = 0; nf < 4; ++nf)
                    acc[mf][nf] = __builtin_amdgcn_mfma_f32_16x16x32_f16(
                        af[mf], bfv[nf], acc[mf][nf], 0, 0, 0);
        }
        __syncthreads();
    }
    // epilogue: C frag layout col = lane&15, row = (lane>>4)*4 + reg
    int j = gm0 >> 11;
    int ibase = (gm0 & (N_ - 1)) + wr * 64 + (lane >> 4) * 4;
#pragma unroll
    for (int nf = 0; nf < 4; ++nf) {
        int d = n0 + wc * 64 + nf * 16 + (lane & 15);
        float cs = 0.f;
#pragma unroll
        for (int mf = 0; mf < 4; ++mf) {
            float v0 = fabsf(acc[mf][nf][0]);
            float v1 = fabsf(acc[mf][nf][1]);
            float v2 = fabsf(acc[mf][nf][2]);
            float v3 = fabsf(acc[mf][nf][3]);
            cs += v0 + v1 + v2 + v3;
            if (MODE == 0) {
                ushort4 o;
                o.x = __half_as_ushort(__float2half(v0));
                o.y = __half_as_ushort(__float2half(v1));
                o.z = __half_as_ushort(__float2half(v2));
                o.w = __half_as_ushort(__float2half(v3));
                *(ushort4*)(U1T + (size_t)(j * 256 + d) * N_ + ibase + mf * 16) = o;
            }
        }
        cs += __shfl_xor(cs, 16);
        cs += __shfl_xor(cs, 32);
        if ((lane >> 4) == 0) {
            int colg = n0 + wc * 64 + nf * 16 + lane;
            if (MODE == 0) atomicAdd(&colsum[j * 256 + colg], cs);
            else atomicAdd(&colsum[(((colg >> 8) * 8 + j) << 8) + (colg & 255)], cs);
        }
    }
}

__global__ __launch_bounds__(256) void fmean_kernel(const float* __restrict__ f, float* __restrict__ out) {
    int d = blockIdx.x, t = threadIdx.x;
    float s = 0.f;
    for (int n = t; n < N_; n += 256) s += f[(size_t)n * DF_ + d];
    __shared__ float red[256];
    red[t] = s; __syncthreads();
    for (int o = 128; o; o >>= 1) { if (t < o) red[t] += red[t + o]; __syncthreads(); }
    if (t == 0) out[d] = red[0] * (1.f / N_);
}

__global__ __launch_bounds__(256) void finalize_kernel(const float* __restrict__ sum1,
                                                       const float* __restrict__ sum2,
                                                       float* __restrict__ out) {
    int idx = blockIdx.x * 256 + threadIdx.x;
    if (idx < 2048)  out[256 + idx]  = sum1[idx] * (1.f / N_);
    if (idx < 16384) out[2304 + idx] = sum2[idx] * (1.f / N_);
}

// ---------------- host orchestration ----------------
extern "C" void kernel_launch(void* const* d_in, const int* in_sizes, int n_in,
                              void* d_out, int out_size, void* d_ws, size_t ws_size,
                              hipStream_t stream) {
    (void)in_sizes; (void)n_in;
    const float* W = (const float*)d_in[0];
    const float* f = (const float*)d_in[1];
    float* out = (float*)d_out;
    char* base = (char*)d_ws;
    size_t off = 0;
    auto take = [&](size_t bytes) -> char* {
        off = (off + 255) & ~(size_t)255;
        char* p = base + off; off += bytes; return p;
    };
    const size_t NSQ = (size_t)N_ * N_;
    float*  dh    = (float*)take((size_t)N_ * 4);
    float*  dr    = (float*)take((size_t)N_ * 4);
    int*    cnt   = (int*)take((size_t)N_ * 4);
    int*    perm  = (int*)take((size_t)N_ * 4);
    int*    cols  = (int*)take((size_t)N_ * ELLW_ * 4);
    float*  vals  = (float*)take((size_t)N_ * ELLW_ * 4);
    float*  coefs = (float*)take((size_t)J_ * M_ * 4);
    float*  sum1  = (float*)take(2048 * 4);
    float*  sum2  = (float*)take(16384 * 4);
    __half* Gh    = (__half*)take(NSQ * 2 * J_);                 //  67.1 MB
    __half* U1T   = (__half*)take((size_t)N_ * 2048 * 2);        //   8.4 MB
    __half* fhT   = (__half*)take((size_t)N_ * DF_ * 2);         //   1.0 MB
    off = (off + 255) & ~(size_t)255;
    const size_t slotBytes = NSQ * 2;
    long long rem = (long long)ws_size - (long long)off;
    int g = (int)(rem / (long long)slotBytes);
    if (g > GCAP_) g = GCAP_;
    if (g < 3) {                       // workspace too small — cannot run
        hipMemsetAsync(d_out, 0, (size_t)out_size * 4, stream);
        return;
    }
    __half* slots = (__half*)take((size_t)g * slotBytes);

    deg_kernel<<<N_, 256, 0, stream>>>(W, dh, dr);
    ell_kernel<<<N_, 64, 0, stream>>>(W, dh, cnt, cols, vals);
    perm_kernel<<<1, 256, 0, stream>>>(cnt, perm);
    coef_kernel<<<J_, 256, 0, stream>>>(coefs);
    hipMemsetAsync(sum1, 0, 2048 * 4, stream);
    hipMemsetAsync(sum2, 0, 16384 * 4, stream);
    init_slots<<<N_, 256, 0, stream>>>(slots, slots + NSQ, cnt, cols, vals, dr);

    int k0 = 0;                        // start of current un-reduced group
    for (int k = 2; k < MUSE_; ++k) {
        cheb_fp16<<<2048, 256, 0, stream>>>(
            slots + (size_t)((k - 1) % g) * NSQ,
            slots + (size_t)((k - 2) % g) * NSQ,
            slots + (size_t)(k % g) * NSQ,
            cnt, cols, vals, dr, perm);
        if (k - k0 + 1 == g || k == MUSE_ - 1) {
            reduce_half<<<2048, 256, 0, stream>>>(slots, g, k0, k - k0 + 1,
                                                  k0 == 0 ? 1 : 0, coefs, Gh);
            k0 = k + 1;
        }
    }
    transpose_f16<<<DF_, 256, 0, stream>>>(f, fhT);
    mfma_gemm<0><<<dim3(2, 128), 256, 0, stream>>>(Gh, fhT, U1T, sum1);
    mfma_gemm<1><<<dim3(16, 128), 256, 0, stream>>>(Gh, U1T, (__half*)nullptr, sum2);
    fmean_kernel<<<DF_, 256, 0, stream>>>(f, out);
    finalize_kernel<<<64, 256, 0, stream>>>(sum1, sum2, out);
}